// Round 8
// baseline (532.763 us; speedup 1.0000x reference)
//
#include <hip/hip_runtime.h>

#define NIN 6
#define HIDN 64
#define NHEAD 4
#define DEGPAD 5   // deg[] stride = 32 words = 128 B: one counter per L2 line

// ---- bf16 pack (RNE) ----
__device__ __forceinline__ unsigned short f2bf(float f) {
    unsigned u = __float_as_uint(f);
    unsigned r = (u >> 16) & 1u;
    return (unsigned short)((u + 0x7fffu + r) >> 16);
}

// ====== fused prelude: hist | consts ONLY (round-3/7 lessons) ==============
// hist is latency-bound: whole-kernel VGPR sets its occupancy (keep ~16).
// encode1 removed: its 25.6MB write stream stretched hist 49->68us (round 2).
__global__ __launch_bounds__(256) void pre_kernel(
    const int* __restrict__ ei, unsigned* __restrict__ deg,
    unsigned* __restrict__ rank, int E,
    const float* __restrict__ w_ee, const float* __restrict__ b_ee,
    const float* __restrict__ w_eg, const float* __restrict__ att_edge,
    float* __restrict__ c1, float* __restrict__ c0,
    int histBlocks) {
    int b = blockIdx.x;
    if (b < histBlocks) {
        int e = b * 256 + threadIdx.x;
        if (e < E) rank[e] = atomicAdd(&deg[(size_t)ei[E + e] << DEGPAD], 1u);
        return;
    }
    // consts: single trailing block, wave-parallel over j (12 (l,h) pairs)
    int w = threadIdx.x >> 6, j = threadIdx.x & 63;
    for (int p = w; p < 12; p += 4) {
        int l = p >> 2, hh = p & 3;
        const float* wr = w_eg + l * 4096 + j * 64 + hh * 16;
        const float* ae = att_edge + l * 64 + hh * 16;
        float wj = 0.f;
#pragma unroll
        for (int d = 0; d < 16; d++) wj += wr[d] * ae[d];
        float s1 = w_ee[j] * wj;
        float s0 = b_ee[j] * wj;
#pragma unroll
        for (int o = 32; o > 0; o >>= 1) {
            s1 += __shfl_xor(s1, o);
            s0 += __shfl_xor(s0, o);
        }
        if (j == 0) { c1[l * 4 + hh] = s1; c0[l * 4 + hh] = s0; }
    }
}

// ====== fused: lookback scan (deg->rp) | FULL per-node encoder chain =======
// Encoder: x -> hid (lane-local) -> h (readlane mm) -> hw16/a_s/a_d (attn0).
// ~128 VGPR is fine HERE: encoder is VALU-bound (3-4 waves/SIMD suffice) and
// scan co-residency holds (4 waves/SIMD -> 1024 resident blocks >> 391).
// Kills the hid round-trip (51MB) and frees sca to be scatter-only.
__global__ __launch_bounds__(256) void mid_kernel(
    const unsigned* __restrict__ deg, unsigned* __restrict__ rp,
    unsigned* __restrict__ st, int N, int E,
    const float* __restrict__ x, const float* __restrict__ w1,
    const float* __restrict__ b1,
    const float* __restrict__ w2, const float* __restrict__ b2,
    const float* __restrict__ wg, const float* __restrict__ att_s_w,
    const float* __restrict__ att_d_w,
    float* __restrict__ h, unsigned short* __restrict__ hw16,
    float* __restrict__ a_s, float* __restrict__ a_d,
    int scanBlocks, int encWaves) {
    int b = blockIdx.x;
    if (b < scanBlocks) {
        __shared__ unsigned sm[256];
        __shared__ unsigned s_prefix;
        int t = threadIdx.x, i = b * 256 + t;
        unsigned v = (i < N) ? deg[(size_t)i << DEGPAD] : 0u;
        sm[t] = v;
        __syncthreads();
        unsigned xx = v;
        for (int o = 1; o < 256; o <<= 1) {
            unsigned add = (t >= o) ? sm[t - o] : 0u;
            __syncthreads();
            xx += add; sm[t] = xx;
            __syncthreads();
        }
        if (t == 255) {
            unsigned tag = (b == 0) ? (2u << 30) : (1u << 30);
            __hip_atomic_store(&st[b], tag | xx, __ATOMIC_RELEASE,
                               __HIP_MEMORY_SCOPE_AGENT);
        }
        if (b == 0) {
            if (t == 0) s_prefix = 0u;
        } else if (t < 64) {
            unsigned pfx = 0u;
            int base = b - 1;
            for (;;) {
                int j = base - t;
                unsigned s;
                for (;;) {
                    s = (j >= 0) ? __hip_atomic_load(&st[j], __ATOMIC_ACQUIRE,
                                                     __HIP_MEMORY_SCOPE_AGENT)
                                 : (2u << 30);
                    if (__all((s >> 30) != 0u)) break;
                }
                unsigned long long m2 = __ballot((s >> 30) == 2u);
                if (m2 != 0ull) {
                    int k = __ffsll(m2) - 1;
                    unsigned val = (t <= k) ? (s & 0x3fffffffu) : 0u;
#pragma unroll
                    for (int o = 32; o > 0; o >>= 1) val += __shfl_xor(val, o);
                    pfx += val;
                    break;
                } else {
                    unsigned val = (j >= 0) ? (s & 0x3fffffffu) : 0u;
#pragma unroll
                    for (int o = 32; o > 0; o >>= 1) val += __shfl_xor(val, o);
                    pfx += val;
                    base -= 64;
                }
            }
            if (t == 0) {
                s_prefix = pfx;
                __hip_atomic_store(&st[b], (2u << 30) | (pfx + sm[255]),
                                   __ATOMIC_RELEASE, __HIP_MEMORY_SCOPE_AGENT);
            }
        }
        __syncthreads();
        if (i < N) rp[i] = (xx - v) + s_prefix;
        if (i == N - 1) rp[N] = (unsigned)E;
        return;
    }
    // ---- fused encoder chain (round-3 verified math) ----
    int j = threadIdx.x & 63;
    float Wa[NIN];
#pragma unroll
    for (int i = 0; i < NIN; i++) Wa[i] = w1[i * HIDN + j];
    float b1j = b1[j];
    float W2c[HIDN];
#pragma unroll
    for (int k = 0; k < HIDN; k++) W2c[k] = w2[k * HIDN + j];
    float b2j = b2[j];
    float Wgc[HIDN];
#pragma unroll
    for (int k = 0; k < HIDN; k++) Wgc[k] = wg[k * HIDN + j];
    float asj = att_s_w[j];
    float adj = att_d_w[j];
    int wv0 = ((b - scanBlocks) * 256 + (int)threadIdx.x) >> 6;
    for (int n0 = wv0; n0 < N; n0 += encWaves) {
        int n = __builtin_amdgcn_readfirstlane(n0);
        // stage 1: hid_j = relu(x@w1 + b1)  (lane-local)
        float hv = b1j;
#pragma unroll
        for (int i = 0; i < NIN; i++) hv += x[(size_t)n * NIN + i] * Wa[i];
        hv = hv > 0.f ? hv : 0.f;
        // stage 2: h_j = sum_k hid_k * w2[k][j]  (readlane broadcast)
        float a0 = 0.f, a1 = 0.f, a2 = 0.f, a3 = 0.f;
#pragma unroll
        for (int kk = 0; kk < 16; kk++) {
            a0 += __shfl(hv, 4 * kk)     * W2c[4 * kk];
            a1 += __shfl(hv, 4 * kk + 1) * W2c[4 * kk + 1];
            a2 += __shfl(hv, 4 * kk + 2) * W2c[4 * kk + 2];
            a3 += __shfl(hv, 4 * kk + 3) * W2c[4 * kk + 3];
        }
        float hcur = ((a0 + a1) + (a2 + a3)) + b2j;
        h[(size_t)n * HIDN + j] = hcur;
        // stage 3: layer-0 attn transform hw = h@w_gat (no bias)
        a0 = a1 = a2 = a3 = 0.f;
#pragma unroll
        for (int kk = 0; kk < 16; kk++) {
            a0 += __shfl(hcur, 4 * kk)     * Wgc[4 * kk];
            a1 += __shfl(hcur, 4 * kk + 1) * Wgc[4 * kk + 1];
            a2 += __shfl(hcur, 4 * kk + 2) * Wgc[4 * kk + 2];
            a3 += __shfl(hcur, 4 * kk + 3) * Wgc[4 * kk + 3];
        }
        float acc = (a0 + a1) + (a2 + a3);
        hw16[(size_t)n * HIDN + j] = f2bf(acc);
        float ts = acc * asj;
        float td = acc * adj;
#pragma unroll
        for (int o = 8; o > 0; o >>= 1) {
            ts += __shfl_xor(ts, o);
            td += __shfl_xor(td, o);
        }
        if ((j & 15) == 0) {
            a_s[(size_t)n * NHEAD + (j >> 4)] = ts;
            a_d[(size_t)n * NHEAD + (j >> 4)] = td;
        }
    }
}

// ====== csr scatter: one packed 8B store per edge, no atomics ==============
__global__ __launch_bounds__(256) void sca_kernel(
    const int* __restrict__ ei, const float* __restrict__ eattr,
    const unsigned* __restrict__ rp, const unsigned* __restrict__ rank,
    int2* __restrict__ eca, int E) {
    int e = blockIdx.x * 256 + threadIdx.x;
    if (e >= E) return;
    int s = ei[e], d = ei[E + e];
    unsigned p = rp[d] + rank[e];
    eca[p] = make_int2(s, __float_as_int(eattr[e]));
}

// ===== fused per-layer edge pipeline + NEXT-LAYER transform epilogue =======
// EXACT round-4 code (73.4us/dispatch measured): no min-waves launch-bounds
// (round-5: forcing 7 blocks/CU spilled, +1.1GB scratch), no mysrc pre-shift
// (round-6: +6us/dispatch), no perm (round-7: eca contiguity loss, +11us).
template <int MODE>
__global__ __launch_bounds__(256) void gat_fused_x_kernel(
    const unsigned* __restrict__ rp, const int2* __restrict__ eca,
    const unsigned short* __restrict__ hw16,
    const float* __restrict__ a_s, const float* __restrict__ a_d,
    const float* __restrict__ c1, const float* __restrict__ c0,
    float* __restrict__ h, const float* __restrict__ bg,
    const float* __restrict__ g, const float* __restrict__ b, int N,
    const float* __restrict__ Wnext,          // 64x64 next transform
    const float* __restrict__ att_s_w, const float* __restrict__ att_d_w,
    const float* __restrict__ bias_out,
    unsigned short* __restrict__ hw16_out,
    float* __restrict__ a_s_out, float* __restrict__ a_d_out,
    float* __restrict__ out) {
    __shared__ float WgL[4096];
    __shared__ float exl[4 * 272];
    __shared__ int srl[4 * 68];

    // stage next-transform weight to LDS (block-uniform, before any return)
    {
        const float4* __restrict__ Wn4 = (const float4*)Wnext;
        float4* WgL4 = (float4*)WgL;
        for (int i = threadIdx.x; i < 1024; i += 256) WgL4[i] = Wn4[i];
    }
    __syncthreads();

    int t = blockIdx.x * blockDim.x + threadIdx.x;
    int lane = t & 63;
    int q = lane >> 4;
    int l = lane & 15;
    int hd = l >> 2;
    int sub = l & 3;
    int n = ((t >> 6) << 2) + q;
    int wslot = (threadIdx.x >> 6);
    float* myex = exl + wslot * 272 + 68 * q;
    int* mysrc = srl + wslot * 68 + 17 * q;

    bool nv = n < N;
    unsigned beg = nv ? rp[n] : 0u;
    int deg = nv ? (int)(rp[n + 1] - beg) : 0;

    float4 ad4 = nv ? *(const float4*)(a_d + ((size_t)n << 2)) : make_float4(0, 0, 0, 0);
    float4 C1 = *(const float4*)c1;
    float4 C0 = *(const float4*)c0;

    int md = deg;
    md = max(md, __shfl_xor(md, 16));
    md = max(md, __shfl_xor(md, 32));
    int chunks = (md + 15) >> 4;

    const unsigned* __restrict__ hwp = (const unsigned*)hw16;
    unsigned loff = (unsigned)(l << 1);

    float ssum = 0.f;
    float ac0 = 0.f, ac1 = 0.f, ac2 = 0.f, ac3 = 0.f;

    for (int k = 0; k < chunks; k++) {
        int i = (k << 4) + l;
        bool act = i < deg;
        int2 ce = act ? eca[beg + i] : make_int2(0, 0);
        int src = ce.x;
        float ea = __int_as_float(ce.y);
        float4 as4 = act ? *(const float4*)(a_s + ((size_t)src << 2))
                         : make_float4(0, 0, 0, 0);
        float s0 = as4.x + ad4.x + ea * C1.x + C0.x;
        float s1 = as4.y + ad4.y + ea * C1.y + C0.y;
        float s2 = as4.z + ad4.z + ea * C1.z + C0.z;
        float s3 = as4.w + ad4.w + ea * C1.w + C0.w;
        s0 = s0 >= 0.f ? s0 : 0.2f * s0;
        s1 = s1 >= 0.f ? s1 : 0.2f * s1;
        s2 = s2 >= 0.f ? s2 : 0.2f * s2;
        s3 = s3 >= 0.f ? s3 : 0.2f * s3;
        float e0 = act ? __expf(s0) : 0.f;
        float e1 = act ? __expf(s1) : 0.f;
        float e2 = act ? __expf(s2) : 0.f;
        float e3 = act ? __expf(s3) : 0.f;
        *(float4*)(myex + (l << 2)) = make_float4(e0, e1, e2, e3);
        mysrc[l] = act ? src : 0;

        float w0 = myex[(sub << 2) + hd];
        float w1 = myex[((sub + 4) << 2) + hd];
        float w2 = myex[((sub + 8) << 2) + hd];
        float w3 = myex[((sub + 12) << 2) + hd];
        float csum = (w0 + w1) + (w2 + w3);
        csum += __shfl_xor(csum, 1);
        csum += __shfl_xor(csum, 2);
        ssum += csum;

#pragma unroll
        for (int e = 0; e < 16; e++) {
            float w = myex[(e << 2) + hd];
            int so = mysrc[e];
            uint2 uu = *(const uint2*)(hwp + (((unsigned)so << 5) + loff));
            ac0 += w * __uint_as_float(uu.x << 16);
            ac1 += w * __uint_as_float(uu.x & 0xffff0000u);
            ac2 += w * __uint_as_float(uu.y << 16);
            ac3 += w * __uint_as_float(uu.y & 0xffff0000u);
        }
    }

    // ---- epilogue: ELU + residual + LayerNorm (values in v0..v3) ----
    float inv = 1.f / (ssum + 1e-16f);
    float4 bg4 = *(const float4*)(bg + (l << 2));
    float4 hv4 = nv ? *(const float4*)(h + (size_t)n * HIDN + (l << 2))
                    : make_float4(0, 0, 0, 0);

    float a0 = ac0 * inv + bg4.x;
    float a1 = ac1 * inv + bg4.y;
    float a2 = ac2 * inv + bg4.z;
    float a3 = ac3 * inv + bg4.w;
    a0 = a0 > 0.f ? a0 : (__expf(a0) - 1.f);
    a1 = a1 > 0.f ? a1 : (__expf(a1) - 1.f);
    a2 = a2 > 0.f ? a2 : (__expf(a2) - 1.f);
    a3 = a3 > 0.f ? a3 : (__expf(a3) - 1.f);
    float v0 = hv4.x + a0, v1 = hv4.y + a1, v2 = hv4.z + a2, v3 = hv4.w + a3;

    float s = (v0 + v1) + (v2 + v3);
    float sq = (v0 * v0 + v1 * v1) + (v2 * v2 + v3 * v3);
#pragma unroll
    for (int o = 8; o > 0; o >>= 1) {
        s += __shfl_xor(s, o);
        sq += __shfl_xor(sq, o);
    }
    float mean = s * (1.f / 64.f);
    float var = sq * (1.f / 64.f) - mean * mean;
    float rr = rsqrtf(var + 1e-5f);
    float4 g4 = *(const float4*)(g + (l << 2));
    float4 b4 = *(const float4*)(b + (l << 2));
    v0 = (v0 - mean) * rr * g4.x + b4.x;
    v1 = (v1 - mean) * rr * g4.y + b4.y;
    v2 = (v2 - mean) * rr * g4.z + b4.z;
    v3 = (v3 - mean) * rr * g4.w + b4.w;

    if (MODE == 0 && nv) {
        // next gat layer's residual read needs h
        *(float4*)(h + (size_t)n * HIDN + (l << 2)) = make_float4(v0, v1, v2, v3);
    }

    // ---- fused next transform: stage h-row to wave-private LDS ----
    float* stg = exl + wslot * 272;               // reuse, wave-private
    *(float4*)(stg + (q << 6) + (l << 2)) = make_float4(v0, v1, v2, v3);

    // each lane computes 4 output columns j = 4l..4l+3 (same MAC order as
    // the encoder/attn bodies -> bit-identical acc values)
    float4 A0 = make_float4(0, 0, 0, 0), A1 = make_float4(0, 0, 0, 0);
    float4 A2 = make_float4(0, 0, 0, 0), A3 = make_float4(0, 0, 0, 0);
#pragma unroll
    for (int kk = 0; kk < 16; kk++) {
        float4 hk = *(const float4*)(stg + (q << 6) + (kk << 2));
        const float* wr = WgL + (kk << 8) + (l << 2);
        float4 w0 = *(const float4*)(wr);
        float4 w1 = *(const float4*)(wr + 64);
        float4 w2 = *(const float4*)(wr + 128);
        float4 w3 = *(const float4*)(wr + 192);
        A0.x += hk.x * w0.x; A0.y += hk.x * w0.y; A0.z += hk.x * w0.z; A0.w += hk.x * w0.w;
        A1.x += hk.y * w1.x; A1.y += hk.y * w1.y; A1.z += hk.y * w1.z; A1.w += hk.y * w1.w;
        A2.x += hk.z * w2.x; A2.y += hk.z * w2.y; A2.z += hk.z * w2.z; A2.w += hk.z * w2.w;
        A3.x += hk.w * w3.x; A3.y += hk.w * w3.y; A3.z += hk.w * w3.z; A3.w += hk.w * w3.w;
    }
    float o0 = (A0.x + A1.x) + (A2.x + A3.x);
    float o1 = (A0.y + A1.y) + (A2.y + A3.y);
    float o2 = (A0.z + A1.z) + (A2.z + A3.z);
    float o3 = (A0.w + A1.w) + (A2.w + A3.w);

    if (MODE == 0) {
        if (nv) {
            ushort4 pk = make_ushort4(f2bf(o0), f2bf(o1), f2bf(o2), f2bf(o3));
            *(ushort4*)(hw16_out + (size_t)n * HIDN + (l << 2)) = pk;
        }
        float4 asw = *(const float4*)(att_s_w + (l << 2));
        float4 adw = *(const float4*)(att_d_w + (l << 2));
        float ts = (o0 * asw.x + o1 * asw.y) + (o2 * asw.z + o3 * asw.w);
        float td = (o0 * adw.x + o1 * adw.y) + (o2 * adw.z + o3 * adw.w);
        ts += __shfl_xor(ts, 1); ts += __shfl_xor(ts, 2);
        td += __shfl_xor(td, 1); td += __shfl_xor(td, 2);
        if (nv && (l & 3) == 0) {
            a_s_out[(size_t)n * NHEAD + (l >> 2)] = ts;
            a_d_out[(size_t)n * NHEAD + (l >> 2)] = td;
        }
    } else {
        if (nv) {
            float4 bo = *(const float4*)(bias_out + (l << 2));
            *(float4*)(out + (size_t)n * HIDN + (l << 2)) =
                make_float4(o0 + bo.x, o1 + bo.y, o2 + bo.z, o3 + bo.w);
        }
    }
}

extern "C" void kernel_launch(void* const* d_in, const int* in_sizes, int n_in,
                              void* d_out, int out_size, void* d_ws, size_t ws_size,
                              hipStream_t stream) {
    const float* x      = (const float*)d_in[0];
    const int*   ei     = (const int*)d_in[1];
    const float* eattr  = (const float*)d_in[2];
    const float* w_ne1  = (const float*)d_in[3];
    const float* b_ne1  = (const float*)d_in[4];
    const float* w_ne2  = (const float*)d_in[5];
    const float* b_ne2  = (const float*)d_in[6];
    const float* w_ee   = (const float*)d_in[7];
    const float* b_ee   = (const float*)d_in[8];
    const float* w_gat  = (const float*)d_in[9];
    const float* w_eg   = (const float*)d_in[10];
    const float* att_src= (const float*)d_in[11];
    const float* att_dst= (const float*)d_in[12];
    const float* att_edge=(const float*)d_in[13];
    const float* b_gat  = (const float*)d_in[14];
    const float* ln_g   = (const float*)d_in[15];
    const float* ln_b   = (const float*)d_in[16];
    const float* w_out  = (const float*)d_in[17];
    const float* b_out  = (const float*)d_in[18];

    const int N = in_sizes[0] / NIN;
    const int E = in_sizes[2];

    // -------- workspace layout --------
    float* ws   = (float*)d_ws;
    float* h    = ws;                                   // N*64
    float* bbuf = h + (size_t)N * 64;                   // N*64 (B-set region)
    unsigned short* hw16 = (unsigned short*)(bbuf + (size_t)N * 64);  // N*64 u16
    float* a_s  = (float*)(hw16 + (size_t)N * 64);      // N*4
    float* a_d  = a_s + (size_t)N * 4;                  // N*4
    float* c1   = a_d + (size_t)N * 4;                  // 12
    float* c0   = c1 + 12;                              // 12
    int2*  eca  = (int2*)(c0 + 12);                     // E int2
    unsigned* rank = (unsigned*)(eca + (size_t)E);      // E
    unsigned* deg  = rank + (size_t)E;                  // N<<DEGPAD (line-padded)
    unsigned* st   = deg + ((size_t)N << DEGPAD);       // 1024 (lookback state)
    unsigned* rp   = st + 1024;                         // N+1

    // ping-pong B-set
    unsigned short* hw16b = (unsigned short*)bbuf;      // N*64 u16 (12.8 MB)
    float* a_sb = (float*)(hw16b + (size_t)N * 64);     // N*4
    float* a_db = a_sb + (size_t)N * 4;                 // N*4

    dim3 blk(256);
    int edgeBlocks = (E + 255) / 256;
    int quadBlocks = (int)(((size_t)((N + 3) / 4) * 64 + 255) / 256);
    int nodeBlocks = (N + 255) / 256;
    int encBlocks = 2048;           // fused-encoder waves inside mid_kernel
    int encWaves  = encBlocks * 4;

    // K0: reset histogram counters + lookback state (adjacent, one memset)
    hipMemsetAsync(deg, 0, (((size_t)N << DEGPAD) + 1024) * sizeof(unsigned), stream);

    // K1: hist (atomic-rate-bound, minimal VGPR) | consts
    pre_kernel<<<edgeBlocks + 1, blk, 0, stream>>>(
        ei, deg, rank, E,
        w_ee, b_ee, w_eg, att_edge, c1, c0,
        edgeBlocks);

    // K2: lookback scan (deg -> rp) | fused encoder (x -> h -> hw16/a_s/a_d)
    mid_kernel<<<nodeBlocks + encBlocks, blk, 0, stream>>>(
        deg, rp, st, N, E,
        x, w_ne1, b_ne1, w_ne2, b_ne2,
        w_gat, att_src, att_dst,
        h, hw16, a_s, a_d,
        nodeBlocks, encWaves);

    // K3: csr scatter (needs rp from mid, rank from pre)
    sca_kernel<<<edgeBlocks, blk, 0, stream>>>(ei, eattr, rp, rank, eca, E);

    // K4: gat layer 0 (reads A) + fused layer-1 transform (writes B)
    gat_fused_x_kernel<0><<<quadBlocks, blk, 0, stream>>>(
        rp, eca, hw16, a_s, a_d, c1 + 0, c0 + 0,
        h, b_gat + 0, ln_g + 0, ln_b + 0, N,
        w_gat + (size_t)1 * 4096, att_src + 64, att_dst + 64, nullptr,
        hw16b, a_sb, a_db, nullptr);

    // K5: gat layer 1 (reads B) + fused layer-2 transform (writes A)
    gat_fused_x_kernel<0><<<quadBlocks, blk, 0, stream>>>(
        rp, eca, hw16b, a_sb, a_db, c1 + 4, c0 + 4,
        h, b_gat + 64, ln_g + 64, ln_b + 64, N,
        w_gat + (size_t)2 * 4096, att_src + 2 * 64, att_dst + 2 * 64, nullptr,
        hw16, a_s, a_d, nullptr);

    // K6: gat layer 2 (reads A) + fused output projection -> d_out
    gat_fused_x_kernel<1><<<quadBlocks, blk, 0, stream>>>(
        rp, eca, hw16, a_s, a_d, c1 + 8, c0 + 8,
        h, b_gat + 2 * 64, ln_g + 2 * 64, ln_b + 2 * 64, N,
        w_out, nullptr, nullptr, b_out,
        nullptr, nullptr, nullptr, (float*)d_out);
}

// Round 9
// 451.410 us; speedup vs baseline: 1.1802x; 1.1802x over previous
//
#include <hip/hip_runtime.h>

#define NIN 6
#define HIDN 64
#define NHEAD 4
#define DEGPAD 5   // deg[] stride = 32 words = 128 B: one counter per L2 line

// ---- bf16 pack (RNE) ----
__device__ __forceinline__ unsigned short f2bf(float f) {
    unsigned u = __float_as_uint(f);
    unsigned r = (u >> 16) & 1u;
    return (unsigned short)((u + 0x7fffu + r) >> 16);
}

// ===== 64x64 fp32 matmul body, weight-stationary, wave-uniform row =========
// (float4 row stream vs register weights — measured fast; the shfl/readlane
//  encoder variant is latency-bound and 6x slower: rounds 3 & 8.)
__device__ __forceinline__ void mm64_plain_body(
    const float* __restrict__ src, const float* __restrict__ W,
    const float* __restrict__ bias, float* __restrict__ dst, int N,
    int wv0, int nw) {
    int j = threadIdx.x & 63;
    float Wc[HIDN];
#pragma unroll
    for (int k = 0; k < HIDN; k++) Wc[k] = W[k * HIDN + j];
    float bj = bias[j];
    for (int n0 = wv0; n0 < N; n0 += nw) {
        int n = __builtin_amdgcn_readfirstlane(n0);
        const float4* __restrict__ row = (const float4*)(src + (size_t)n * HIDN);
        float a0 = 0.f, a1 = 0.f, a2 = 0.f, a3 = 0.f;
#pragma unroll
        for (int kk = 0; kk < 16; kk++) {
            float4 r = row[kk];
            a0 += r.x * Wc[4 * kk];
            a1 += r.y * Wc[4 * kk + 1];
            a2 += r.z * Wc[4 * kk + 2];
            a3 += r.w * Wc[4 * kk + 3];
        }
        dst[(size_t)n * HIDN + j] = ((a0 + a1) + (a2 + a3)) + bj;
    }
}

// ===== same matmul, bf16 out (gather buffer) + a_s/a_d head dots ===========
__device__ __forceinline__ void mm64_attn_body(
    const float* __restrict__ src, const float* __restrict__ W,
    const float* __restrict__ att_s, const float* __restrict__ att_d,
    unsigned short* __restrict__ dst16,
    float* __restrict__ a_s, float* __restrict__ a_d, int N,
    int wv0, int nw) {
    int j = threadIdx.x & 63;
    float Wc[HIDN];
#pragma unroll
    for (int k = 0; k < HIDN; k++) Wc[k] = W[k * HIDN + j];
    float asj = att_s[j];
    float adj = att_d[j];
    for (int n0 = wv0; n0 < N; n0 += nw) {
        int n = __builtin_amdgcn_readfirstlane(n0);
        const float4* __restrict__ row = (const float4*)(src + (size_t)n * HIDN);
        float a0 = 0.f, a1 = 0.f, a2 = 0.f, a3 = 0.f;
#pragma unroll
        for (int kk = 0; kk < 16; kk++) {
            float4 r = row[kk];
            a0 += r.x * Wc[4 * kk];
            a1 += r.y * Wc[4 * kk + 1];
            a2 += r.z * Wc[4 * kk + 2];
            a3 += r.w * Wc[4 * kk + 3];
        }
        float acc = (a0 + a1) + (a2 + a3);
        dst16[(size_t)n * HIDN + j] = f2bf(acc);
        float ts = acc * asj;
        float td = acc * adj;
#pragma unroll
        for (int o = 8; o > 0; o >>= 1) {
            ts += __shfl_xor(ts, o);
            td += __shfl_xor(td, o);
        }
        if ((j & 15) == 0) {
            a_s[(size_t)n * NHEAD + (j >> 4)] = ts;
            a_d[(size_t)n * NHEAD + (j >> 4)] = td;
        }
    }
}

// ====== fused prelude: hist | encode1 | consts (LOW VGPR — keep it so) =====
// Round-3/8 lessons: hist is latency-bound; whole-kernel VGPR sets its
// occupancy. encode1 uses only Wa[6] -> 28 VGPR, 71% occupancy, 68us.
__global__ __launch_bounds__(256) void pre_kernel(
    const int* __restrict__ ei, unsigned* __restrict__ deg,
    unsigned* __restrict__ rank, int E,
    const float* __restrict__ x, const float* __restrict__ w1,
    const float* __restrict__ b1, float* __restrict__ hid, int N,
    const float* __restrict__ w_ee, const float* __restrict__ b_ee,
    const float* __restrict__ w_eg, const float* __restrict__ att_edge,
    float* __restrict__ c1, float* __restrict__ c0,
    int histBlocks, int encBlocks) {
    int b = blockIdx.x;
    if (b < histBlocks) {
        int e = b * 256 + threadIdx.x;
        if (e < E) rank[e] = atomicAdd(&deg[(size_t)ei[E + e] << DEGPAD], 1u);
        return;
    }
    b -= histBlocks;
    if (b < encBlocks) {
        int t = b * 256 + threadIdx.x;
        int n = t >> 6, j = t & 63;
        if (n >= N) return;
        float acc = b1[j];
#pragma unroll
        for (int i = 0; i < NIN; i++) acc += x[n * NIN + i] * w1[i * HIDN + j];
        hid[(size_t)n * HIDN + j] = acc > 0.f ? acc : 0.f;
        return;
    }
    int w = threadIdx.x >> 6, j = threadIdx.x & 63;
    for (int p = w; p < 12; p += 4) {
        int l = p >> 2, hh = p & 3;
        const float* wr = w_eg + l * 4096 + j * 64 + hh * 16;
        const float* ae = att_edge + l * 64 + hh * 16;
        float wj = 0.f;
#pragma unroll
        for (int d = 0; d < 16; d++) wj += wr[d] * ae[d];
        float s1 = w_ee[j] * wj;
        float s0 = b_ee[j] * wj;
#pragma unroll
        for (int o = 32; o > 0; o >>= 1) {
            s1 += __shfl_xor(s1, o);
            s0 += __shfl_xor(s0, o);
        }
        if (j == 0) { c1[l * 4 + hh] = s1; c0[l * 4 + hh] = s0; }
    }
}

// ====== fused: single-pass lookback scan of deg -> rp | encoder mm =========
// Decoupled lookback: st[b] packs (status<<30 | value). mm blocks (2048)
// guarantee scan co-residency (391 blocks << capacity) -> no deadlock.
__global__ __launch_bounds__(256) void mid_kernel(
    const unsigned* __restrict__ deg, unsigned* __restrict__ rp,
    unsigned* __restrict__ st, int N, int E,
    const float* __restrict__ src, const float* __restrict__ W,
    const float* __restrict__ bias, float* __restrict__ dst,
    int scanBlocks, int mmWaves) {
    int b = blockIdx.x;
    if (b < scanBlocks) {
        __shared__ unsigned sm[256];
        __shared__ unsigned s_prefix;
        int t = threadIdx.x, i = b * 256 + t;
        unsigned v = (i < N) ? deg[(size_t)i << DEGPAD] : 0u;
        sm[t] = v;
        __syncthreads();
        unsigned xx = v;
        for (int o = 1; o < 256; o <<= 1) {
            unsigned add = (t >= o) ? sm[t - o] : 0u;
            __syncthreads();
            xx += add; sm[t] = xx;
            __syncthreads();
        }
        if (t == 255) {
            unsigned tag = (b == 0) ? (2u << 30) : (1u << 30);
            __hip_atomic_store(&st[b], tag | xx, __ATOMIC_RELEASE,
                               __HIP_MEMORY_SCOPE_AGENT);
        }
        if (b == 0) {
            if (t == 0) s_prefix = 0u;
        } else if (t < 64) {
            unsigned pfx = 0u;
            int base = b - 1;
            for (;;) {
                int j = base - t;
                unsigned s;
                for (;;) {
                    s = (j >= 0) ? __hip_atomic_load(&st[j], __ATOMIC_ACQUIRE,
                                                     __HIP_MEMORY_SCOPE_AGENT)
                                 : (2u << 30);
                    if (__all((s >> 30) != 0u)) break;
                }
                unsigned long long m2 = __ballot((s >> 30) == 2u);
                if (m2 != 0ull) {
                    int k = __ffsll(m2) - 1;
                    unsigned val = (t <= k) ? (s & 0x3fffffffu) : 0u;
#pragma unroll
                    for (int o = 32; o > 0; o >>= 1) val += __shfl_xor(val, o);
                    pfx += val;
                    break;
                } else {
                    unsigned val = (j >= 0) ? (s & 0x3fffffffu) : 0u;
#pragma unroll
                    for (int o = 32; o > 0; o >>= 1) val += __shfl_xor(val, o);
                    pfx += val;
                    base -= 64;
                }
            }
            if (t == 0) {
                s_prefix = pfx;
                __hip_atomic_store(&st[b], (2u << 30) | (pfx + sm[255]),
                                   __ATOMIC_RELEASE, __HIP_MEMORY_SCOPE_AGENT);
            }
        }
        __syncthreads();
        if (i < N) rp[i] = (xx - v) + s_prefix;
        if (i == N - 1) rp[N] = (unsigned)E;
        return;
    }
    int wv0 = ((b - scanBlocks) * 256 + threadIdx.x) >> 6;
    mm64_plain_body(src, W, bias, dst, N, wv0, mmWaves);
}

// ====== fused: csr_scatter | layer-0 mm64_attn (both deps satisfied) =======
__global__ __launch_bounds__(256) void sca_kernel(
    const int* __restrict__ ei, const float* __restrict__ eattr,
    const unsigned* __restrict__ rp, const unsigned* __restrict__ rank,
    int2* __restrict__ eca, int E,
    const float* __restrict__ src, const float* __restrict__ W,
    const float* __restrict__ att_s, const float* __restrict__ att_d,
    unsigned short* __restrict__ dst16,
    float* __restrict__ a_s, float* __restrict__ a_d, int N,
    int scatBlocks, int mmWaves) {
    int b = blockIdx.x;
    if (b < scatBlocks) {
        int e = b * 256 + threadIdx.x;
        if (e >= E) return;
        int s = ei[e], d = ei[E + e];
        unsigned p = rp[d] + rank[e];
        eca[p] = make_int2(s, __float_as_int(eattr[e]));
        return;
    }
    int wv0 = ((b - scatBlocks) * 256 + threadIdx.x) >> 6;
    mm64_attn_body(src, W, att_s, att_d, dst16, a_s, a_d, N, wv0, mmWaves);
}

// ===== fused per-layer edge pipeline + NEXT-LAYER transform epilogue =======
// EXACT round-4 body (73.4us measured). Kept out: min-waves launch-bounds
// (round-5 spill disaster), mysrc pre-shift (round-6 +6us), perm (round-7
// eca contiguity loss). gat is at its random-gather floor: E x 128B/layer
// at ~2TB/s effective ~= 73us.
template <int MODE>
__global__ __launch_bounds__(256) void gat_fused_x_kernel(
    const unsigned* __restrict__ rp, const int2* __restrict__ eca,
    const unsigned short* __restrict__ hw16,
    const float* __restrict__ a_s, const float* __restrict__ a_d,
    const float* __restrict__ c1, const float* __restrict__ c0,
    float* __restrict__ h, const float* __restrict__ bg,
    const float* __restrict__ g, const float* __restrict__ b, int N,
    const float* __restrict__ Wnext,          // 64x64 next transform
    const float* __restrict__ att_s_w, const float* __restrict__ att_d_w,
    const float* __restrict__ bias_out,
    unsigned short* __restrict__ hw16_out,
    float* __restrict__ a_s_out, float* __restrict__ a_d_out,
    float* __restrict__ out) {
    __shared__ float WgL[4096];
    __shared__ float exl[4 * 272];
    __shared__ int srl[4 * 68];

    // stage next-transform weight to LDS (block-uniform, before any return)
    {
        const float4* __restrict__ Wn4 = (const float4*)Wnext;
        float4* WgL4 = (float4*)WgL;
        for (int i = threadIdx.x; i < 1024; i += 256) WgL4[i] = Wn4[i];
    }
    __syncthreads();

    int t = blockIdx.x * blockDim.x + threadIdx.x;
    int lane = t & 63;
    int q = lane >> 4;
    int l = lane & 15;
    int hd = l >> 2;
    int sub = l & 3;
    int n = ((t >> 6) << 2) + q;
    int wslot = (threadIdx.x >> 6);
    float* myex = exl + wslot * 272 + 68 * q;
    int* mysrc = srl + wslot * 68 + 17 * q;

    bool nv = n < N;
    unsigned beg = nv ? rp[n] : 0u;
    int deg = nv ? (int)(rp[n + 1] - beg) : 0;

    float4 ad4 = nv ? *(const float4*)(a_d + ((size_t)n << 2)) : make_float4(0, 0, 0, 0);
    float4 C1 = *(const float4*)c1;
    float4 C0 = *(const float4*)c0;

    int md = deg;
    md = max(md, __shfl_xor(md, 16));
    md = max(md, __shfl_xor(md, 32));
    int chunks = (md + 15) >> 4;

    const unsigned* __restrict__ hwp = (const unsigned*)hw16;
    unsigned loff = (unsigned)(l << 1);

    float ssum = 0.f;
    float ac0 = 0.f, ac1 = 0.f, ac2 = 0.f, ac3 = 0.f;

    for (int k = 0; k < chunks; k++) {
        int i = (k << 4) + l;
        bool act = i < deg;
        int2 ce = act ? eca[beg + i] : make_int2(0, 0);
        int src = ce.x;
        float ea = __int_as_float(ce.y);
        float4 as4 = act ? *(const float4*)(a_s + ((size_t)src << 2))
                         : make_float4(0, 0, 0, 0);
        float s0 = as4.x + ad4.x + ea * C1.x + C0.x;
        float s1 = as4.y + ad4.y + ea * C1.y + C0.y;
        float s2 = as4.z + ad4.z + ea * C1.z + C0.z;
        float s3 = as4.w + ad4.w + ea * C1.w + C0.w;
        s0 = s0 >= 0.f ? s0 : 0.2f * s0;
        s1 = s1 >= 0.f ? s1 : 0.2f * s1;
        s2 = s2 >= 0.f ? s2 : 0.2f * s2;
        s3 = s3 >= 0.f ? s3 : 0.2f * s3;
        float e0 = act ? __expf(s0) : 0.f;
        float e1 = act ? __expf(s1) : 0.f;
        float e2 = act ? __expf(s2) : 0.f;
        float e3 = act ? __expf(s3) : 0.f;
        *(float4*)(myex + (l << 2)) = make_float4(e0, e1, e2, e3);
        mysrc[l] = act ? src : 0;

        float w0 = myex[(sub << 2) + hd];
        float w1 = myex[((sub + 4) << 2) + hd];
        float w2 = myex[((sub + 8) << 2) + hd];
        float w3 = myex[((sub + 12) << 2) + hd];
        float csum = (w0 + w1) + (w2 + w3);
        csum += __shfl_xor(csum, 1);
        csum += __shfl_xor(csum, 2);
        ssum += csum;

#pragma unroll
        for (int e = 0; e < 16; e++) {
            float w = myex[(e << 2) + hd];
            int so = mysrc[e];
            uint2 uu = *(const uint2*)(hwp + (((unsigned)so << 5) + loff));
            ac0 += w * __uint_as_float(uu.x << 16);
            ac1 += w * __uint_as_float(uu.x & 0xffff0000u);
            ac2 += w * __uint_as_float(uu.y << 16);
            ac3 += w * __uint_as_float(uu.y & 0xffff0000u);
        }
    }

    // ---- epilogue: ELU + residual + LayerNorm (values in v0..v3) ----
    float inv = 1.f / (ssum + 1e-16f);
    float4 bg4 = *(const float4*)(bg + (l << 2));
    float4 hv4 = nv ? *(const float4*)(h + (size_t)n * HIDN + (l << 2))
                    : make_float4(0, 0, 0, 0);

    float a0 = ac0 * inv + bg4.x;
    float a1 = ac1 * inv + bg4.y;
    float a2 = ac2 * inv + bg4.z;
    float a3 = ac3 * inv + bg4.w;
    a0 = a0 > 0.f ? a0 : (__expf(a0) - 1.f);
    a1 = a1 > 0.f ? a1 : (__expf(a1) - 1.f);
    a2 = a2 > 0.f ? a2 : (__expf(a2) - 1.f);
    a3 = a3 > 0.f ? a3 : (__expf(a3) - 1.f);
    float v0 = hv4.x + a0, v1 = hv4.y + a1, v2 = hv4.z + a2, v3 = hv4.w + a3;

    float s = (v0 + v1) + (v2 + v3);
    float sq = (v0 * v0 + v1 * v1) + (v2 * v2 + v3 * v3);
#pragma unroll
    for (int o = 8; o > 0; o >>= 1) {
        s += __shfl_xor(s, o);
        sq += __shfl_xor(sq, o);
    }
    float mean = s * (1.f / 64.f);
    float var = sq * (1.f / 64.f) - mean * mean;
    float rr = rsqrtf(var + 1e-5f);
    float4 g4 = *(const float4*)(g + (l << 2));
    float4 b4 = *(const float4*)(b + (l << 2));
    v0 = (v0 - mean) * rr * g4.x + b4.x;
    v1 = (v1 - mean) * rr * g4.y + b4.y;
    v2 = (v2 - mean) * rr * g4.z + b4.z;
    v3 = (v3 - mean) * rr * g4.w + b4.w;

    if (MODE == 0 && nv) {
        // next gat layer's residual read needs h
        *(float4*)(h + (size_t)n * HIDN + (l << 2)) = make_float4(v0, v1, v2, v3);
    }

    // ---- fused next transform: stage h-row to wave-private LDS ----
    float* stg = exl + wslot * 272;               // reuse, wave-private
    *(float4*)(stg + (q << 6) + (l << 2)) = make_float4(v0, v1, v2, v3);

    // each lane computes 4 output columns j = 4l..4l+3 (same MAC order as
    // mm64_attn_body / mm64_plain_body -> bit-identical acc values)
    float4 A0 = make_float4(0, 0, 0, 0), A1 = make_float4(0, 0, 0, 0);
    float4 A2 = make_float4(0, 0, 0, 0), A3 = make_float4(0, 0, 0, 0);
#pragma unroll
    for (int kk = 0; kk < 16; kk++) {
        float4 hk = *(const float4*)(stg + (q << 6) + (kk << 2));
        const float* wr = WgL + (kk << 8) + (l << 2);
        float4 w0 = *(const float4*)(wr);
        float4 w1 = *(const float4*)(wr + 64);
        float4 w2 = *(const float4*)(wr + 128);
        float4 w3 = *(const float4*)(wr + 192);
        A0.x += hk.x * w0.x; A0.y += hk.x * w0.y; A0.z += hk.x * w0.z; A0.w += hk.x * w0.w;
        A1.x += hk.y * w1.x; A1.y += hk.y * w1.y; A1.z += hk.y * w1.z; A1.w += hk.y * w1.w;
        A2.x += hk.z * w2.x; A2.y += hk.z * w2.y; A2.z += hk.z * w2.z; A2.w += hk.z * w2.w;
        A3.x += hk.w * w3.x; A3.y += hk.w * w3.y; A3.z += hk.w * w3.z; A3.w += hk.w * w3.w;
    }
    float o0 = (A0.x + A1.x) + (A2.x + A3.x);
    float o1 = (A0.y + A1.y) + (A2.y + A3.y);
    float o2 = (A0.z + A1.z) + (A2.z + A3.z);
    float o3 = (A0.w + A1.w) + (A2.w + A3.w);

    if (MODE == 0) {
        if (nv) {
            ushort4 pk = make_ushort4(f2bf(o0), f2bf(o1), f2bf(o2), f2bf(o3));
            *(ushort4*)(hw16_out + (size_t)n * HIDN + (l << 2)) = pk;
        }
        float4 asw = *(const float4*)(att_s_w + (l << 2));
        float4 adw = *(const float4*)(att_d_w + (l << 2));
        float ts = (o0 * asw.x + o1 * asw.y) + (o2 * asw.z + o3 * asw.w);
        float td = (o0 * adw.x + o1 * adw.y) + (o2 * adw.z + o3 * adw.w);
        ts += __shfl_xor(ts, 1); ts += __shfl_xor(ts, 2);
        td += __shfl_xor(td, 1); td += __shfl_xor(td, 2);
        if (nv && (l & 3) == 0) {
            a_s_out[(size_t)n * NHEAD + (l >> 2)] = ts;
            a_d_out[(size_t)n * NHEAD + (l >> 2)] = td;
        }
    } else {
        if (nv) {
            float4 bo = *(const float4*)(bias_out + (l << 2));
            *(float4*)(out + (size_t)n * HIDN + (l << 2)) =
                make_float4(o0 + bo.x, o1 + bo.y, o2 + bo.z, o3 + bo.w);
        }
    }
}

extern "C" void kernel_launch(void* const* d_in, const int* in_sizes, int n_in,
                              void* d_out, int out_size, void* d_ws, size_t ws_size,
                              hipStream_t stream) {
    const float* x      = (const float*)d_in[0];
    const int*   ei     = (const int*)d_in[1];
    const float* eattr  = (const float*)d_in[2];
    const float* w_ne1  = (const float*)d_in[3];
    const float* b_ne1  = (const float*)d_in[4];
    const float* w_ne2  = (const float*)d_in[5];
    const float* b_ne2  = (const float*)d_in[6];
    const float* w_ee   = (const float*)d_in[7];
    const float* b_ee   = (const float*)d_in[8];
    const float* w_gat  = (const float*)d_in[9];
    const float* w_eg   = (const float*)d_in[10];
    const float* att_src= (const float*)d_in[11];
    const float* att_dst= (const float*)d_in[12];
    const float* att_edge=(const float*)d_in[13];
    const float* b_gat  = (const float*)d_in[14];
    const float* ln_g   = (const float*)d_in[15];
    const float* ln_b   = (const float*)d_in[16];
    const float* w_out  = (const float*)d_in[17];
    const float* b_out  = (const float*)d_in[18];

    const int N = in_sizes[0] / NIN;
    const int E = in_sizes[2];

    // -------- workspace layout --------
    float* ws   = (float*)d_ws;
    float* h    = ws;                                   // N*64
    float* hid  = h + (size_t)N * 64;                   // N*64 (dead after mid)
    unsigned short* hw16 = (unsigned short*)(hid + (size_t)N * 64);  // N*64 u16
    float* a_s  = (float*)(hw16 + (size_t)N * 64);      // N*4
    float* a_d  = a_s + (size_t)N * 4;                  // N*4
    float* c1   = a_d + (size_t)N * 4;                  // 12
    float* c0   = c1 + 12;                              // 12
    int2*  eca  = (int2*)(c0 + 12);                     // E int2
    unsigned* rank = (unsigned*)(eca + (size_t)E);      // E
    unsigned* deg  = rank + (size_t)E;                  // N<<DEGPAD (line-padded)
    unsigned* st   = deg + ((size_t)N << DEGPAD);       // 1024 (lookback state)
    unsigned* rp   = st + 1024;                         // N+1

    // ping-pong B-set carved from hid (dead after mid_kernel)
    unsigned short* hw16b = (unsigned short*)hid;       // N*64 u16 (12.8 MB)
    float* a_sb = (float*)(hw16b + (size_t)N * 64);     // N*4
    float* a_db = a_sb + (size_t)N * 4;                 // N*4

    dim3 blk(256);
    int edgeBlocks = (E + 255) / 256;
    int encBlocks  = (int)(((size_t)N * 64 + 255) / 256);
    int quadBlocks = (int)(((size_t)((N + 3) / 4) * 64 + 255) / 256);
    int nodeBlocks = (N + 255) / 256;
    int mmBlocks = 2048;            // 8192 waves, grid-stride over nodes
    int mmWaves  = mmBlocks * 4;

    // K0: reset histogram counters + lookback state (adjacent, one memset)
    hipMemsetAsync(deg, 0, (((size_t)N << DEGPAD) + 1024) * sizeof(unsigned), stream);

    // K1: hist (atomic-rate-bound, low-VGPR) | encode1 | consts
    pre_kernel<<<edgeBlocks + encBlocks + 1, blk, 0, stream>>>(
        ei, deg, rank, E,
        x, w_ne1, b_ne1, hid, N,
        w_ee, b_ee, w_eg, att_edge, c1, c0,
        edgeBlocks, encBlocks);

    // K2: single-pass lookback scan (deg -> rp) | encoder mm (hid@w2 -> h)
    mid_kernel<<<nodeBlocks + mmBlocks, blk, 0, stream>>>(
        deg, rp, st, N, E, hid, w_ne2, b_ne2, h, nodeBlocks, mmWaves);

    // K3: csr scatter | layer-0 attn transform (h -> hw16/a_s/a_d, A-set)
    sca_kernel<<<edgeBlocks + mmBlocks, blk, 0, stream>>>(
        ei, eattr, rp, rank, eca, E,
        h, w_gat, att_src, att_dst, hw16, a_s, a_d, N,
        edgeBlocks, mmWaves);

    // K4: gat layer 0 (reads A) + fused layer-1 transform (writes B)
    gat_fused_x_kernel<0><<<quadBlocks, blk, 0, stream>>>(
        rp, eca, hw16, a_s, a_d, c1 + 0, c0 + 0,
        h, b_gat + 0, ln_g + 0, ln_b + 0, N,
        w_gat + (size_t)1 * 4096, att_src + 64, att_dst + 64, nullptr,
        hw16b, a_sb, a_db, nullptr);

    // K5: gat layer 1 (reads B) + fused layer-2 transform (writes A)
    gat_fused_x_kernel<0><<<quadBlocks, blk, 0, stream>>>(
        rp, eca, hw16b, a_sb, a_db, c1 + 4, c0 + 4,
        h, b_gat + 64, ln_g + 64, ln_b + 64, N,
        w_gat + (size_t)2 * 4096, att_src + 2 * 64, att_dst + 2 * 64, nullptr,
        hw16, a_s, a_d, nullptr);

    // K6: gat layer 2 (reads A) + fused output projection -> d_out
    gat_fused_x_kernel<1><<<quadBlocks, blk, 0, stream>>>(
        rp, eca, hw16, a_s, a_d, c1 + 8, c0 + 8,
        h, b_gat + 2 * 64, ln_g + 2 * 64, ln_b + 2 * 64, N,
        w_out, nullptr, nullptr, b_out,
        nullptr, nullptr, nullptr, (float*)d_out);
}

// Round 11
// 440.515 us; speedup vs baseline: 1.2094x; 1.0247x over previous
//
#include <hip/hip_runtime.h>

#define NIN 6
#define HIDN 64
#define NHEAD 4
#define DEGPAD 5   // deg[] stride = 32 words = 128 B: one counter per L2 line

// ---- bf16 pack (RNE) ----
__device__ __forceinline__ unsigned short f2bf(float f) {
    unsigned u = __float_as_uint(f);
    unsigned r = (u >> 16) & 1u;
    return (unsigned short)((u + 0x7fffu + r) >> 16);
}

// ===== 64x64 fp32 matmul body, bf16 out (gather buffer) + a_s/a_d dots =====
__device__ __forceinline__ void mm64_attn_body(
    const float* __restrict__ src, const float* __restrict__ W,
    const float* __restrict__ att_s, const float* __restrict__ att_d,
    unsigned short* __restrict__ dst16,
    float* __restrict__ a_s, float* __restrict__ a_d, int N,
    int wv0, int nw) {
    int j = threadIdx.x & 63;
    float Wc[HIDN];
#pragma unroll
    for (int k = 0; k < HIDN; k++) Wc[k] = W[k * HIDN + j];
    float asj = att_s[j];
    float adj = att_d[j];
    for (int n0 = wv0; n0 < N; n0 += nw) {
        int n = __builtin_amdgcn_readfirstlane(n0);
        const float4* __restrict__ row = (const float4*)(src + (size_t)n * HIDN);
        float a0 = 0.f, a1 = 0.f, a2 = 0.f, a3 = 0.f;
#pragma unroll
        for (int kk = 0; kk < 16; kk++) {
            float4 r = row[kk];
            a0 += r.x * Wc[4 * kk];
            a1 += r.y * Wc[4 * kk + 1];
            a2 += r.z * Wc[4 * kk + 2];
            a3 += r.w * Wc[4 * kk + 3];
        }
        float acc = (a0 + a1) + (a2 + a3);
        dst16[(size_t)n * HIDN + j] = f2bf(acc);
        float ts = acc * asj;
        float td = acc * adj;
#pragma unroll
        for (int o = 8; o > 0; o >>= 1) {
            ts += __shfl_xor(ts, o);
            td += __shfl_xor(td, o);
        }
        if ((j & 15) == 0) {
            a_s[(size_t)n * NHEAD + (j >> 4)] = ts;
            a_d[(size_t)n * NHEAD + (j >> 4)] = td;
        }
    }
}

// ====== fused prelude: hist | consts (hist back to its ~49us floor) ========
// Round-2 lesson: encode1's 25.6MB write stream stretched hist 49->68us;
// encoder now lives in mid. Whole-kernel VGPR stays minimal for occupancy.
__global__ __launch_bounds__(256) void pre_kernel(
    const int* __restrict__ ei, unsigned* __restrict__ deg,
    unsigned* __restrict__ rank, int E,
    const float* __restrict__ w_ee, const float* __restrict__ b_ee,
    const float* __restrict__ w_eg, const float* __restrict__ att_edge,
    float* __restrict__ c1, float* __restrict__ c0,
    int histBlocks) {
    int b = blockIdx.x;
    if (b < histBlocks) {
        int e = b * 256 + threadIdx.x;
        if (e < E) rank[e] = atomicAdd(&deg[(size_t)ei[E + e] << DEGPAD], 1u);
        return;
    }
    // consts: single trailing block, wave-parallel over j (12 (l,h) pairs)
    int w = threadIdx.x >> 6, j = threadIdx.x & 63;
    for (int p = w; p < 12; p += 4) {
        int l = p >> 2, hh = p & 3;
        const float* wr = w_eg + l * 4096 + j * 64 + hh * 16;
        const float* ae = att_edge + l * 64 + hh * 16;
        float wj = 0.f;
#pragma unroll
        for (int d = 0; d < 16; d++) wj += wr[d] * ae[d];
        float s1 = w_ee[j] * wj;
        float s0 = b_ee[j] * wj;
#pragma unroll
        for (int o = 32; o > 0; o >>= 1) {
            s1 += __shfl_xor(s1, o);
            s0 += __shfl_xor(s0, o);
        }
        if (j == 0) { c1[l * 4 + hh] = s1; c0[l * 4 + hh] = s0; }
    }
}

// ====== fused: lookback scan (deg->rp) | encode1+mm fused via LDS row ======
// Encoder: lane j computes hid_j (lane-local, Wa[6]), stages the 64-float row
// in wave-private LDS, then runs the EXACT mm64_plain 4-acc MAC loop reading
// the row from LDS (same-address broadcast, conflict-free) with W2c[64] in
// registers. No shfl chains (rounds 3/8 killer), no 51MB hid round-trip.
// ~96 VGPR is fine here: only hist is occupancy-critical. Scan co-residency:
// 391 scan blocks << capacity even at 5 blocks/CU -> lookback can't deadlock.
__global__ __launch_bounds__(256) void mid_kernel(
    const unsigned* __restrict__ deg, unsigned* __restrict__ rp,
    unsigned* __restrict__ st, int N, int E,
    const float* __restrict__ x, const float* __restrict__ w1,
    const float* __restrict__ b1,
    const float* __restrict__ w2, const float* __restrict__ b2,
    float* __restrict__ h,
    int scanBlocks, int encWaves) {
    __shared__ unsigned sm[256];
    __shared__ unsigned s_prefix;
    int b = blockIdx.x;
    if (b < scanBlocks) {
        int t = threadIdx.x, i = b * 256 + t;
        unsigned v = (i < N) ? deg[(size_t)i << DEGPAD] : 0u;
        sm[t] = v;
        __syncthreads();
        unsigned xx = v;
        for (int o = 1; o < 256; o <<= 1) {
            unsigned add = (t >= o) ? sm[t - o] : 0u;
            __syncthreads();
            xx += add; sm[t] = xx;
            __syncthreads();
        }
        if (t == 255) {
            unsigned tag = (b == 0) ? (2u << 30) : (1u << 30);
            __hip_atomic_store(&st[b], tag | xx, __ATOMIC_RELEASE,
                               __HIP_MEMORY_SCOPE_AGENT);
        }
        if (b == 0) {
            if (t == 0) s_prefix = 0u;
        } else if (t < 64) {
            unsigned pfx = 0u;
            int base = b - 1;
            for (;;) {
                int j = base - t;
                unsigned s;
                for (;;) {
                    s = (j >= 0) ? __hip_atomic_load(&st[j], __ATOMIC_ACQUIRE,
                                                     __HIP_MEMORY_SCOPE_AGENT)
                                 : (2u << 30);
                    if (__all((s >> 30) != 0u)) break;
                }
                unsigned long long m2 = __ballot((s >> 30) == 2u);
                if (m2 != 0ull) {
                    int k = __ffsll(m2) - 1;
                    unsigned val = (t <= k) ? (s & 0x3fffffffu) : 0u;
#pragma unroll
                    for (int o = 32; o > 0; o >>= 1) val += __shfl_xor(val, o);
                    pfx += val;
                    break;
                } else {
                    unsigned val = (j >= 0) ? (s & 0x3fffffffu) : 0u;
#pragma unroll
                    for (int o = 32; o > 0; o >>= 1) val += __shfl_xor(val, o);
                    pfx += val;
                    base -= 64;
                }
            }
            if (t == 0) {
                s_prefix = pfx;
                __hip_atomic_store(&st[b], (2u << 30) | (pfx + sm[255]),
                                   __ATOMIC_RELEASE, __HIP_MEMORY_SCOPE_AGENT);
            }
        }
        __syncthreads();
        if (i < N) rp[i] = (xx - v) + s_prefix;
        if (i == N - 1) rp[N] = (unsigned)E;
        return;
    }
    // ---- fused encoder: x -> hid (lane-local) -> LDS row -> h (float4 MAC)
    int j = threadIdx.x & 63;
    int wv = threadIdx.x >> 6;
    float* hidL = ((float*)sm) + wv * 64;       // wave-private 64-float slot
    float Wa[NIN];
#pragma unroll
    for (int i = 0; i < NIN; i++) Wa[i] = w1[i * HIDN + j];
    float b1j = b1[j];
    float W2c[HIDN];
#pragma unroll
    for (int k = 0; k < HIDN; k++) W2c[k] = w2[k * HIDN + j];
    float b2j = b2[j];
    int wv0 = ((b - scanBlocks) * 256 + (int)threadIdx.x) >> 6;
    for (int n0 = wv0; n0 < N; n0 += encWaves) {
        int n = __builtin_amdgcn_readfirstlane(n0);
        // stage 1: hid_j = relu(x@w1 + b1)  (identical math to encode1)
        float hv = b1j;
#pragma unroll
        for (int i = 0; i < NIN; i++) hv += x[(size_t)n * NIN + i] * Wa[i];
        hv = hv > 0.f ? hv : 0.f;
        hidL[j] = hv;
        __builtin_amdgcn_wave_barrier();        // order LDS write vs reads
        // stage 2: h_j — EXACT mm64_plain 4-acc MAC order (bit-identical)
        float a0 = 0.f, a1 = 0.f, a2 = 0.f, a3 = 0.f;
#pragma unroll
        for (int kk = 0; kk < 16; kk++) {
            float4 r = *(const float4*)(hidL + (kk << 2));
            a0 += r.x * W2c[4 * kk];
            a1 += r.y * W2c[4 * kk + 1];
            a2 += r.z * W2c[4 * kk + 2];
            a3 += r.w * W2c[4 * kk + 3];
        }
        __builtin_amdgcn_wave_barrier();        // reads done before next write
        h[(size_t)n * HIDN + j] = ((a0 + a1) + (a2 + a3)) + b2j;
    }
}

// ====== fused: csr_scatter | layer-0 mm64_attn (both deps satisfied) =======
__global__ __launch_bounds__(256) void sca_kernel(
    const int* __restrict__ ei, const float* __restrict__ eattr,
    const unsigned* __restrict__ rp, const unsigned* __restrict__ rank,
    int2* __restrict__ eca, int E,
    const float* __restrict__ src, const float* __restrict__ W,
    const float* __restrict__ att_s, const float* __restrict__ att_d,
    unsigned short* __restrict__ dst16,
    float* __restrict__ a_s, float* __restrict__ a_d, int N,
    int scatBlocks, int mmWaves) {
    int b = blockIdx.x;
    if (b < scatBlocks) {
        int e = b * 256 + threadIdx.x;
        if (e >= E) return;
        int s = ei[e], d = ei[E + e];
        unsigned p = rp[d] + rank[e];
        eca[p] = make_int2(s, __float_as_int(eattr[e]));
        return;
    }
    int wv0 = ((b - scatBlocks) * 256 + threadIdx.x) >> 6;
    mm64_attn_body(src, W, att_s, att_d, dst16, a_s, a_d, N, wv0, mmWaves);
}

// ===== fused per-layer edge pipeline + NEXT-LAYER transform epilogue =======
// EXACT round-4 body (73.4us measured, reproduced round 9). Kept out:
// min-waves launch-bounds (r5 spill), mysrc pre-shift (r6 +6us), perm (r7
// eca contiguity loss). gat sits at its random-gather floor (~2TB/s mixed).
template <int MODE>
__global__ __launch_bounds__(256) void gat_fused_x_kernel(
    const unsigned* __restrict__ rp, const int2* __restrict__ eca,
    const unsigned short* __restrict__ hw16,
    const float* __restrict__ a_s, const float* __restrict__ a_d,
    const float* __restrict__ c1, const float* __restrict__ c0,
    float* __restrict__ h, const float* __restrict__ bg,
    const float* __restrict__ g, const float* __restrict__ b, int N,
    const float* __restrict__ Wnext,          // 64x64 next transform
    const float* __restrict__ att_s_w, const float* __restrict__ att_d_w,
    const float* __restrict__ bias_out,
    unsigned short* __restrict__ hw16_out,
    float* __restrict__ a_s_out, float* __restrict__ a_d_out,
    float* __restrict__ out) {
    __shared__ float WgL[4096];
    __shared__ float exl[4 * 272];
    __shared__ int srl[4 * 68];

    // stage next-transform weight to LDS (block-uniform, before any return)
    {
        const float4* __restrict__ Wn4 = (const float4*)Wnext;
        float4* WgL4 = (float4*)WgL;
        for (int i = threadIdx.x; i < 1024; i += 256) WgL4[i] = Wn4[i];
    }
    __syncthreads();

    int t = blockIdx.x * blockDim.x + threadIdx.x;
    int lane = t & 63;
    int q = lane >> 4;
    int l = lane & 15;
    int hd = l >> 2;
    int sub = l & 3;
    int n = ((t >> 6) << 2) + q;
    int wslot = (threadIdx.x >> 6);
    float* myex = exl + wslot * 272 + 68 * q;
    int* mysrc = srl + wslot * 68 + 17 * q;

    bool nv = n < N;
    unsigned beg = nv ? rp[n] : 0u;
    int deg = nv ? (int)(rp[n + 1] - beg) : 0;

    float4 ad4 = nv ? *(const float4*)(a_d + ((size_t)n << 2)) : make_float4(0, 0, 0, 0);
    float4 C1 = *(const float4*)c1;
    float4 C0 = *(const float4*)c0;

    int md = deg;
    md = max(md, __shfl_xor(md, 16));
    md = max(md, __shfl_xor(md, 32));
    int chunks = (md + 15) >> 4;

    const unsigned* __restrict__ hwp = (const unsigned*)hw16;
    unsigned loff = (unsigned)(l << 1);

    float ssum = 0.f;
    float ac0 = 0.f, ac1 = 0.f, ac2 = 0.f, ac3 = 0.f;

    for (int k = 0; k < chunks; k++) {
        int i = (k << 4) + l;
        bool act = i < deg;
        int2 ce = act ? eca[beg + i] : make_int2(0, 0);
        int src = ce.x;
        float ea = __int_as_float(ce.y);
        float4 as4 = act ? *(const float4*)(a_s + ((size_t)src << 2))
                         : make_float4(0, 0, 0, 0);
        float s0 = as4.x + ad4.x + ea * C1.x + C0.x;
        float s1 = as4.y + ad4.y + ea * C1.y + C0.y;
        float s2 = as4.z + ad4.z + ea * C1.z + C0.z;
        float s3 = as4.w + ad4.w + ea * C1.w + C0.w;
        s0 = s0 >= 0.f ? s0 : 0.2f * s0;
        s1 = s1 >= 0.f ? s1 : 0.2f * s1;
        s2 = s2 >= 0.f ? s2 : 0.2f * s2;
        s3 = s3 >= 0.f ? s3 : 0.2f * s3;
        float e0 = act ? __expf(s0) : 0.f;
        float e1 = act ? __expf(s1) : 0.f;
        float e2 = act ? __expf(s2) : 0.f;
        float e3 = act ? __expf(s3) : 0.f;
        *(float4*)(myex + (l << 2)) = make_float4(e0, e1, e2, e3);
        mysrc[l] = act ? src : 0;

        float w0 = myex[(sub << 2) + hd];
        float w1 = myex[((sub + 4) << 2) + hd];
        float w2 = myex[((sub + 8) << 2) + hd];
        float w3 = myex[((sub + 12) << 2) + hd];
        float csum = (w0 + w1) + (w2 + w3);
        csum += __shfl_xor(csum, 1);
        csum += __shfl_xor(csum, 2);
        ssum += csum;

#pragma unroll
        for (int e = 0; e < 16; e++) {
            float w = myex[(e << 2) + hd];
            int so = mysrc[e];
            uint2 uu = *(const uint2*)(hwp + (((unsigned)so << 5) + loff));
            ac0 += w * __uint_as_float(uu.x << 16);
            ac1 += w * __uint_as_float(uu.x & 0xffff0000u);
            ac2 += w * __uint_as_float(uu.y << 16);
            ac3 += w * __uint_as_float(uu.y & 0xffff0000u);
        }
    }

    // ---- epilogue: ELU + residual + LayerNorm (values in v0..v3) ----
    float inv = 1.f / (ssum + 1e-16f);
    float4 bg4 = *(const float4*)(bg + (l << 2));
    float4 hv4 = nv ? *(const float4*)(h + (size_t)n * HIDN + (l << 2))
                    : make_float4(0, 0, 0, 0);

    float a0 = ac0 * inv + bg4.x;
    float a1 = ac1 * inv + bg4.y;
    float a2 = ac2 * inv + bg4.z;
    float a3 = ac3 * inv + bg4.w;
    a0 = a0 > 0.f ? a0 : (__expf(a0) - 1.f);
    a1 = a1 > 0.f ? a1 : (__expf(a1) - 1.f);
    a2 = a2 > 0.f ? a2 : (__expf(a2) - 1.f);
    a3 = a3 > 0.f ? a3 : (__expf(a3) - 1.f);
    float v0 = hv4.x + a0, v1 = hv4.y + a1, v2 = hv4.z + a2, v3 = hv4.w + a3;

    float s = (v0 + v1) + (v2 + v3);
    float sq = (v0 * v0 + v1 * v1) + (v2 * v2 + v3 * v3);
#pragma unroll
    for (int o = 8; o > 0; o >>= 1) {
        s += __shfl_xor(s, o);
        sq += __shfl_xor(sq, o);
    }
    float mean = s * (1.f / 64.f);
    float var = sq * (1.f / 64.f) - mean * mean;
    float rr = rsqrtf(var + 1e-5f);
    float4 g4 = *(const float4*)(g + (l << 2));
    float4 b4 = *(const float4*)(b + (l << 2));
    v0 = (v0 - mean) * rr * g4.x + b4.x;
    v1 = (v1 - mean) * rr * g4.y + b4.y;
    v2 = (v2 - mean) * rr * g4.z + b4.z;
    v3 = (v3 - mean) * rr * g4.w + b4.w;

    if (MODE == 0 && nv) {
        // next gat layer's residual read needs h
        *(float4*)(h + (size_t)n * HIDN + (l << 2)) = make_float4(v0, v1, v2, v3);
    }

    // ---- fused next transform: stage h-row to wave-private LDS ----
    float* stg = exl + wslot * 272;               // reuse, wave-private
    *(float4*)(stg + (q << 6) + (l << 2)) = make_float4(v0, v1, v2, v3);

    // each lane computes 4 output columns j = 4l..4l+3 (same MAC order as
    // mm64_attn_body / the fused encoder -> bit-identical acc values)
    float4 A0 = make_float4(0, 0, 0, 0), A1 = make_float4(0, 0, 0, 0);
    float4 A2 = make_float4(0, 0, 0, 0), A3 = make_float4(0, 0, 0, 0);
#pragma unroll
    for (int kk = 0; kk < 16; kk++) {
        float4 hk = *(const float4*)(stg + (q << 6) + (kk << 2));
        const float* wr = WgL + (kk << 8) + (l << 2);
        float4 w0 = *(const float4*)(wr);
        float4 w1 = *(const float4*)(wr + 64);
        float4 w2 = *(const float4*)(wr + 128);
        float4 w3 = *(const float4*)(wr + 192);
        A0.x += hk.x * w0.x; A0.y += hk.x * w0.y; A0.z += hk.x * w0.z; A0.w += hk.x * w0.w;
        A1.x += hk.y * w1.x; A1.y += hk.y * w1.y; A1.z += hk.y * w1.z; A1.w += hk.y * w1.w;
        A2.x += hk.z * w2.x; A2.y += hk.z * w2.y; A2.z += hk.z * w2.z; A2.w += hk.z * w2.w;
        A3.x += hk.w * w3.x; A3.y += hk.w * w3.y; A3.z += hk.w * w3.z; A3.w += hk.w * w3.w;
    }
    float o0 = (A0.x + A1.x) + (A2.x + A3.x);
    float o1 = (A0.y + A1.y) + (A2.y + A3.y);
    float o2 = (A0.z + A1.z) + (A2.z + A3.z);
    float o3 = (A0.w + A1.w) + (A2.w + A3.w);

    if (MODE == 0) {
        if (nv) {
            ushort4 pk = make_ushort4(f2bf(o0), f2bf(o1), f2bf(o2), f2bf(o3));
            *(ushort4*)(hw16_out + (size_t)n * HIDN + (l << 2)) = pk;
        }
        float4 asw = *(const float4*)(att_s_w + (l << 2));
        float4 adw = *(const float4*)(att_d_w + (l << 2));
        float ts = (o0 * asw.x + o1 * asw.y) + (o2 * asw.z + o3 * asw.w);
        float td = (o0 * adw.x + o1 * adw.y) + (o2 * adw.z + o3 * adw.w);
        ts += __shfl_xor(ts, 1); ts += __shfl_xor(ts, 2);
        td += __shfl_xor(td, 1); td += __shfl_xor(td, 2);
        if (nv && (l & 3) == 0) {
            a_s_out[(size_t)n * NHEAD + (l >> 2)] = ts;
            a_d_out[(size_t)n * NHEAD + (l >> 2)] = td;
        }
    } else {
        if (nv) {
            float4 bo = *(const float4*)(bias_out + (l << 2));
            *(float4*)(out + (size_t)n * HIDN + (l << 2)) =
                make_float4(o0 + bo.x, o1 + bo.y, o2 + bo.z, o3 + bo.w);
        }
    }
}

extern "C" void kernel_launch(void* const* d_in, const int* in_sizes, int n_in,
                              void* d_out, int out_size, void* d_ws, size_t ws_size,
                              hipStream_t stream) {
    const float* x      = (const float*)d_in[0];
    const int*   ei     = (const int*)d_in[1];
    const float* eattr  = (const float*)d_in[2];
    const float* w_ne1  = (const float*)d_in[3];
    const float* b_ne1  = (const float*)d_in[4];
    const float* w_ne2  = (const float*)d_in[5];
    const float* b_ne2  = (const float*)d_in[6];
    const float* w_ee   = (const float*)d_in[7];
    const float* b_ee   = (const float*)d_in[8];
    const float* w_gat  = (const float*)d_in[9];
    const float* w_eg   = (const float*)d_in[10];
    const float* att_src= (const float*)d_in[11];
    const float* att_dst= (const float*)d_in[12];
    const float* att_edge=(const float*)d_in[13];
    const float* b_gat  = (const float*)d_in[14];
    const float* ln_g   = (const float*)d_in[15];
    const float* ln_b   = (const float*)d_in[16];
    const float* w_out  = (const float*)d_in[17];
    const float* b_out  = (const float*)d_in[18];

    const int N = in_sizes[0] / NIN;
    const int E = in_sizes[2];

    // -------- workspace layout --------
    float* ws   = (float*)d_ws;
    float* h    = ws;                                   // N*64
    float* bbuf = h + (size_t)N * 64;                   // N*64 (B-set region)
    unsigned short* hw16 = (unsigned short*)(bbuf + (size_t)N * 64);  // N*64 u16
    float* a_s  = (float*)(hw16 + (size_t)N * 64);      // N*4
    float* a_d  = a_s + (size_t)N * 4;                  // N*4
    float* c1   = a_d + (size_t)N * 4;                  // 12
    float* c0   = c1 + 12;                              // 12
    int2*  eca  = (int2*)(c0 + 12);                     // E int2
    unsigned* rank = (unsigned*)(eca + (size_t)E);      // E
    unsigned* deg  = rank + (size_t)E;                  // N<<DEGPAD (line-padded)
    unsigned* st   = deg + ((size_t)N << DEGPAD);       // 1024 (lookback state)
    unsigned* rp   = st + 1024;                         // N+1

    // ping-pong B-set
    unsigned short* hw16b = (unsigned short*)bbuf;      // N*64 u16 (12.8 MB)
    float* a_sb = (float*)(hw16b + (size_t)N * 64);     // N*4
    float* a_db = a_sb + (size_t)N * 4;                 // N*4

    dim3 blk(256);
    int edgeBlocks = (E + 255) / 256;
    int quadBlocks = (int)(((size_t)((N + 3) / 4) * 64 + 255) / 256);
    int nodeBlocks = (N + 255) / 256;
    int mmBlocks = 2048;            // 8192 waves, grid-stride over nodes
    int mmWaves  = mmBlocks * 4;
    int encBlocks = 2048;           // fused-encoder blocks inside mid
    int encWaves  = encBlocks * 4;

    // K0: reset histogram counters + lookback state (adjacent, one memset)
    hipMemsetAsync(deg, 0, (((size_t)N << DEGPAD) + 1024) * sizeof(unsigned), stream);

    // K1: hist (atomic-rate-bound, minimal VGPR) | consts
    pre_kernel<<<edgeBlocks + 1, blk, 0, stream>>>(
        ei, deg, rank, E,
        w_ee, b_ee, w_eg, att_edge, c1, c0,
        edgeBlocks);

    // K2: lookback scan (deg -> rp) | fused encoder (x -> h, LDS row stage)
    mid_kernel<<<nodeBlocks + encBlocks, blk, 0, stream>>>(
        deg, rp, st, N, E,
        x, w_ne1, b_ne1, w_ne2, b_ne2, h,
        nodeBlocks, encWaves);

    // K3: csr scatter | layer-0 attn transform (h -> hw16/a_s/a_d, A-set)
    sca_kernel<<<edgeBlocks + mmBlocks, blk, 0, stream>>>(
        ei, eattr, rp, rank, eca, E,
        h, w_gat, att_src, att_dst, hw16, a_s, a_d, N,
        edgeBlocks, mmWaves);

    // K4: gat layer 0 (reads A) + fused layer-1 transform (writes B)
    gat_fused_x_kernel<0><<<quadBlocks, blk, 0, stream>>>(
        rp, eca, hw16, a_s, a_d, c1 + 0, c0 + 0,
        h, b_gat + 0, ln_g + 0, ln_b + 0, N,
        w_gat + (size_t)1 * 4096, att_src + 64, att_dst + 64, nullptr,
        hw16b, a_sb, a_db, nullptr);

    // K5: gat layer 1 (reads B) + fused layer-2 transform (writes A)
    gat_fused_x_kernel<0><<<quadBlocks, blk, 0, stream>>>(
        rp, eca, hw16b, a_sb, a_db, c1 + 4, c0 + 4,
        h, b_gat + 64, ln_g + 64, ln_b + 64, N,
        w_gat + (size_t)2 * 4096, att_src + 2 * 64, att_dst + 2 * 64, nullptr,
        hw16, a_s, a_d, nullptr);

    // K6: gat layer 2 (reads A) + fused output projection -> d_out
    gat_fused_x_kernel<1><<<quadBlocks, blk, 0, stream>>>(
        rp, eca, hw16, a_s, a_d, c1 + 8, c0 + 8,
        h, b_gat + 2 * 64, ln_g + 2 * 64, ln_b + 2 * 64, N,
        w_out, nullptr, nullptr, b_out,
        nullptr, nullptr, nullptr, (float*)d_out);
}

// Round 12
// 427.779 us; speedup vs baseline: 1.2454x; 1.0298x over previous
//
#include <hip/hip_runtime.h>

#define NIN 6
#define HIDN 64
#define NHEAD 4
#define DEGPAD 5   // deg[] stride = 32 words = 128 B: one counter per L2 line

// ---- bf16 pack (RNE) ----
__device__ __forceinline__ unsigned short f2bf(float f) {
    unsigned u = __float_as_uint(f);
    unsigned r = (u >> 16) & 1u;
    return (unsigned short)((u + 0x7fffu + r) >> 16);
}

// ===== 64x64 fp32 matmul body, weight-stationary, wave-uniform row =========
// (float4 row stream vs register weights; shfl/readlane and LDS-staged
//  encoder variants measured slower: rounds 3, 8, 11.)
__device__ __forceinline__ void mm64_plain_body(
    const float* __restrict__ src, const float* __restrict__ W,
    const float* __restrict__ bias, float* __restrict__ dst, int N,
    int wv0, int nw) {
    int j = threadIdx.x & 63;
    float Wc[HIDN];
#pragma unroll
    for (int k = 0; k < HIDN; k++) Wc[k] = W[k * HIDN + j];
    float bj = bias[j];
    for (int n0 = wv0; n0 < N; n0 += nw) {
        int n = __builtin_amdgcn_readfirstlane(n0);
        const float4* __restrict__ row = (const float4*)(src + (size_t)n * HIDN);
        float a0 = 0.f, a1 = 0.f, a2 = 0.f, a3 = 0.f;
#pragma unroll
        for (int kk = 0; kk < 16; kk++) {
            float4 r = row[kk];
            a0 += r.x * Wc[4 * kk];
            a1 += r.y * Wc[4 * kk + 1];
            a2 += r.z * Wc[4 * kk + 2];
            a3 += r.w * Wc[4 * kk + 3];
        }
        dst[(size_t)n * HIDN + j] = ((a0 + a1) + (a2 + a3)) + bj;
    }
}

// ===== same matmul, bf16 out (gather buffer) + a_s/a_d head dots ===========
__device__ __forceinline__ void mm64_attn_body(
    const float* __restrict__ src, const float* __restrict__ W,
    const float* __restrict__ att_s, const float* __restrict__ att_d,
    unsigned short* __restrict__ dst16,
    float* __restrict__ a_s, float* __restrict__ a_d, int N,
    int wv0, int nw) {
    int j = threadIdx.x & 63;
    float Wc[HIDN];
#pragma unroll
    for (int k = 0; k < HIDN; k++) Wc[k] = W[k * HIDN + j];
    float asj = att_s[j];
    float adj = att_d[j];
    for (int n0 = wv0; n0 < N; n0 += nw) {
        int n = __builtin_amdgcn_readfirstlane(n0);
        const float4* __restrict__ row = (const float4*)(src + (size_t)n * HIDN);
        float a0 = 0.f, a1 = 0.f, a2 = 0.f, a3 = 0.f;
#pragma unroll
        for (int kk = 0; kk < 16; kk++) {
            float4 r = row[kk];
            a0 += r.x * Wc[4 * kk];
            a1 += r.y * Wc[4 * kk + 1];
            a2 += r.z * Wc[4 * kk + 2];
            a3 += r.w * Wc[4 * kk + 3];
        }
        float acc = (a0 + a1) + (a2 + a3);
        dst16[(size_t)n * HIDN + j] = f2bf(acc);
        float ts = acc * asj;
        float td = acc * adj;
#pragma unroll
        for (int o = 8; o > 0; o >>= 1) {
            ts += __shfl_xor(ts, o);
            td += __shfl_xor(td, o);
        }
        if ((j & 15) == 0) {
            a_s[(size_t)n * NHEAD + (j >> 4)] = ts;
            a_d[(size_t)n * NHEAD + (j >> 4)] = td;
        }
    }
}

// ====== fused prelude: hist | encode1 | consts (LOW VGPR — keep it so) =====
// hist is latency-bound; whole-kernel VGPR sets its occupancy (r3/r8 lesson).
// encode1 uses only Wa[6] -> 28 VGPR, 71% occupancy, 68us measured (r4/r6).
__global__ __launch_bounds__(256) void pre_kernel(
    const int* __restrict__ ei, unsigned* __restrict__ deg,
    unsigned* __restrict__ rank, int E,
    const float* __restrict__ x, const float* __restrict__ w1,
    const float* __restrict__ b1, float* __restrict__ hid, int N,
    const float* __restrict__ w_ee, const float* __restrict__ b_ee,
    const float* __restrict__ w_eg, const float* __restrict__ att_edge,
    float* __restrict__ c1, float* __restrict__ c0,
    int histBlocks, int encBlocks) {
    int b = blockIdx.x;
    if (b < histBlocks) {
        int e = b * 256 + threadIdx.x;
        if (e < E) rank[e] = atomicAdd(&deg[(size_t)ei[E + e] << DEGPAD], 1u);
        return;
    }
    b -= histBlocks;
    if (b < encBlocks) {
        int t = b * 256 + threadIdx.x;
        int n = t >> 6, j = t & 63;
        if (n >= N) return;
        float acc = b1[j];
#pragma unroll
        for (int i = 0; i < NIN; i++) acc += x[n * NIN + i] * w1[i * HIDN + j];
        hid[(size_t)n * HIDN + j] = acc > 0.f ? acc : 0.f;
        return;
    }
    int w = threadIdx.x >> 6, j = threadIdx.x & 63;
    for (int p = w; p < 12; p += 4) {
        int l = p >> 2, hh = p & 3;
        const float* wr = w_eg + l * 4096 + j * 64 + hh * 16;
        const float* ae = att_edge + l * 64 + hh * 16;
        float wj = 0.f;
#pragma unroll
        for (int d = 0; d < 16; d++) wj += wr[d] * ae[d];
        float s1 = w_ee[j] * wj;
        float s0 = b_ee[j] * wj;
#pragma unroll
        for (int o = 32; o > 0; o >>= 1) {
            s1 += __shfl_xor(s1, o);
            s0 += __shfl_xor(s0, o);
        }
        if (j == 0) { c1[l * 4 + hh] = s1; c0[l * 4 + hh] = s0; }
    }
}

// ====== fused: scan1 (block-local prefix of deg) | encoder mm64_plain ======
// r4-vs-r9 lesson: the decoupled-lookback single-pass scan SPINS on
// device-scope loads and contends with the co-dispatched mm (+20us);
// scan1 + tiny scan23 dispatch is measured faster. Keep this form.
__global__ __launch_bounds__(256) void mid_kernel(
    const unsigned* __restrict__ deg, unsigned* __restrict__ rp,
    unsigned* __restrict__ bsum, int N,
    const float* __restrict__ src, const float* __restrict__ W,
    const float* __restrict__ bias, float* __restrict__ dst,
    int scanBlocks, int mmWaves) {
    __shared__ unsigned sm[256];
    int b = blockIdx.x;
    if (b < scanBlocks) {
        int t = threadIdx.x, i = b * 256 + t;
        unsigned v = (i < N) ? deg[(size_t)i << DEGPAD] : 0u;
        sm[t] = v;
        __syncthreads();
        unsigned xx = v;
        for (int o = 1; o < 256; o <<= 1) {
            unsigned add = (t >= o) ? sm[t - o] : 0u;
            __syncthreads();
            xx += add; sm[t] = xx;
            __syncthreads();
        }
        if (i < N) rp[i] = xx - v;
        if (t == 255) bsum[b] = xx;
        return;
    }
    int wv0 = ((b - scanBlocks) * 256 + threadIdx.x) >> 6;
    mm64_plain_body(src, W, bias, dst, N, wv0, mmWaves);
}

// ====== merged scan2+scan3: each block redundantly reduces block sums ======
__global__ __launch_bounds__(256) void scan23_kernel(
    unsigned* __restrict__ rp, const unsigned* __restrict__ bsum,
    int N, int E) {
    __shared__ unsigned red[256];
    int b = blockIdx.x, t = threadIdx.x;
    unsigned partial = 0;
    for (int j = t; j < b; j += 256) partial += bsum[j];
    red[t] = partial;
    __syncthreads();
    for (int o = 128; o > 0; o >>= 1) {
        if (t < o) red[t] += red[t + o];
        __syncthreads();
    }
    unsigned off = red[0];
    int i = b * 256 + t;
    if (i < N) rp[i] += off;
    if (b == 0 && t == 0) rp[N] = (unsigned)E;
}

// ====== fused: csr_scatter | layer-0 mm64_attn (both deps satisfied) =======
__global__ __launch_bounds__(256) void sca_kernel(
    const int* __restrict__ ei, const float* __restrict__ eattr,
    const unsigned* __restrict__ rp, const unsigned* __restrict__ rank,
    int2* __restrict__ eca, int E,
    const float* __restrict__ src, const float* __restrict__ W,
    const float* __restrict__ att_s, const float* __restrict__ att_d,
    unsigned short* __restrict__ dst16,
    float* __restrict__ a_s, float* __restrict__ a_d, int N,
    int scatBlocks, int mmWaves) {
    int b = blockIdx.x;
    if (b < scatBlocks) {
        int e = b * 256 + threadIdx.x;
        if (e >= E) return;
        int s = ei[e], d = ei[E + e];
        unsigned p = rp[d] + rank[e];
        eca[p] = make_int2(s, __float_as_int(eattr[e]));
        return;
    }
    int wv0 = ((b - scatBlocks) * 256 + threadIdx.x) >> 6;
    mm64_attn_body(src, W, att_s, att_d, dst16, a_s, a_d, N, wv0, mmWaves);
}

// ===== fused per-layer edge pipeline + NEXT-LAYER transform epilogue =======
// EXACT round-4 body — 73.4us measured, reproduced rounds 9/11. Kept out:
// min-waves launch-bounds (r5: spill, +1.1GB scratch), mysrc pre-shift
// (r6: +6us), perm reorder (r7: eca contiguity loss, +17us). This kernel
// runs at its random-gather floor (~2TB/s effective L2-miss bandwidth).
template <int MODE>
__global__ __launch_bounds__(256) void gat_fused_x_kernel(
    const unsigned* __restrict__ rp, const int2* __restrict__ eca,
    const unsigned short* __restrict__ hw16,
    const float* __restrict__ a_s, const float* __restrict__ a_d,
    const float* __restrict__ c1, const float* __restrict__ c0,
    float* __restrict__ h, const float* __restrict__ bg,
    const float* __restrict__ g, const float* __restrict__ b, int N,
    const float* __restrict__ Wnext,          // 64x64 next transform
    const float* __restrict__ att_s_w, const float* __restrict__ att_d_w,
    const float* __restrict__ bias_out,
    unsigned short* __restrict__ hw16_out,
    float* __restrict__ a_s_out, float* __restrict__ a_d_out,
    float* __restrict__ out) {
    __shared__ float WgL[4096];
    __shared__ float exl[4 * 272];
    __shared__ int srl[4 * 68];

    // stage next-transform weight to LDS (block-uniform, before any return)
    {
        const float4* __restrict__ Wn4 = (const float4*)Wnext;
        float4* WgL4 = (float4*)WgL;
        for (int i = threadIdx.x; i < 1024; i += 256) WgL4[i] = Wn4[i];
    }
    __syncthreads();

    int t = blockIdx.x * blockDim.x + threadIdx.x;
    int lane = t & 63;
    int q = lane >> 4;
    int l = lane & 15;
    int hd = l >> 2;
    int sub = l & 3;
    int n = ((t >> 6) << 2) + q;
    int wslot = (threadIdx.x >> 6);
    float* myex = exl + wslot * 272 + 68 * q;
    int* mysrc = srl + wslot * 68 + 17 * q;

    bool nv = n < N;
    unsigned beg = nv ? rp[n] : 0u;
    int deg = nv ? (int)(rp[n + 1] - beg) : 0;

    float4 ad4 = nv ? *(const float4*)(a_d + ((size_t)n << 2)) : make_float4(0, 0, 0, 0);
    float4 C1 = *(const float4*)c1;
    float4 C0 = *(const float4*)c0;

    int md = deg;
    md = max(md, __shfl_xor(md, 16));
    md = max(md, __shfl_xor(md, 32));
    int chunks = (md + 15) >> 4;

    const unsigned* __restrict__ hwp = (const unsigned*)hw16;
    unsigned loff = (unsigned)(l << 1);

    float ssum = 0.f;
    float ac0 = 0.f, ac1 = 0.f, ac2 = 0.f, ac3 = 0.f;

    for (int k = 0; k < chunks; k++) {
        int i = (k << 4) + l;
        bool act = i < deg;
        int2 ce = act ? eca[beg + i] : make_int2(0, 0);
        int src = ce.x;
        float ea = __int_as_float(ce.y);
        float4 as4 = act ? *(const float4*)(a_s + ((size_t)src << 2))
                         : make_float4(0, 0, 0, 0);
        float s0 = as4.x + ad4.x + ea * C1.x + C0.x;
        float s1 = as4.y + ad4.y + ea * C1.y + C0.y;
        float s2 = as4.z + ad4.z + ea * C1.z + C0.z;
        float s3 = as4.w + ad4.w + ea * C1.w + C0.w;
        s0 = s0 >= 0.f ? s0 : 0.2f * s0;
        s1 = s1 >= 0.f ? s1 : 0.2f * s1;
        s2 = s2 >= 0.f ? s2 : 0.2f * s2;
        s3 = s3 >= 0.f ? s3 : 0.2f * s3;
        float e0 = act ? __expf(s0) : 0.f;
        float e1 = act ? __expf(s1) : 0.f;
        float e2 = act ? __expf(s2) : 0.f;
        float e3 = act ? __expf(s3) : 0.f;
        *(float4*)(myex + (l << 2)) = make_float4(e0, e1, e2, e3);
        mysrc[l] = act ? src : 0;

        float w0 = myex[(sub << 2) + hd];
        float w1 = myex[((sub + 4) << 2) + hd];
        float w2 = myex[((sub + 8) << 2) + hd];
        float w3 = myex[((sub + 12) << 2) + hd];
        float csum = (w0 + w1) + (w2 + w3);
        csum += __shfl_xor(csum, 1);
        csum += __shfl_xor(csum, 2);
        ssum += csum;

#pragma unroll
        for (int e = 0; e < 16; e++) {
            float w = myex[(e << 2) + hd];
            int so = mysrc[e];
            uint2 uu = *(const uint2*)(hwp + (((unsigned)so << 5) + loff));
            ac0 += w * __uint_as_float(uu.x << 16);
            ac1 += w * __uint_as_float(uu.x & 0xffff0000u);
            ac2 += w * __uint_as_float(uu.y << 16);
            ac3 += w * __uint_as_float(uu.y & 0xffff0000u);
        }
    }

    // ---- epilogue: ELU + residual + LayerNorm (values in v0..v3) ----
    float inv = 1.f / (ssum + 1e-16f);
    float4 bg4 = *(const float4*)(bg + (l << 2));
    float4 hv4 = nv ? *(const float4*)(h + (size_t)n * HIDN + (l << 2))
                    : make_float4(0, 0, 0, 0);

    float a0 = ac0 * inv + bg4.x;
    float a1 = ac1 * inv + bg4.y;
    float a2 = ac2 * inv + bg4.z;
    float a3 = ac3 * inv + bg4.w;
    a0 = a0 > 0.f ? a0 : (__expf(a0) - 1.f);
    a1 = a1 > 0.f ? a1 : (__expf(a1) - 1.f);
    a2 = a2 > 0.f ? a2 : (__expf(a2) - 1.f);
    a3 = a3 > 0.f ? a3 : (__expf(a3) - 1.f);
    float v0 = hv4.x + a0, v1 = hv4.y + a1, v2 = hv4.z + a2, v3 = hv4.w + a3;

    float s = (v0 + v1) + (v2 + v3);
    float sq = (v0 * v0 + v1 * v1) + (v2 * v2 + v3 * v3);
#pragma unroll
    for (int o = 8; o > 0; o >>= 1) {
        s += __shfl_xor(s, o);
        sq += __shfl_xor(sq, o);
    }
    float mean = s * (1.f / 64.f);
    float var = sq * (1.f / 64.f) - mean * mean;
    float rr = rsqrtf(var + 1e-5f);
    float4 g4 = *(const float4*)(g + (l << 2));
    float4 b4 = *(const float4*)(b + (l << 2));
    v0 = (v0 - mean) * rr * g4.x + b4.x;
    v1 = (v1 - mean) * rr * g4.y + b4.y;
    v2 = (v2 - mean) * rr * g4.z + b4.z;
    v3 = (v3 - mean) * rr * g4.w + b4.w;

    if (MODE == 0 && nv) {
        // next gat layer's residual read needs h
        *(float4*)(h + (size_t)n * HIDN + (l << 2)) = make_float4(v0, v1, v2, v3);
    }

    // ---- fused next transform: stage h-row to wave-private LDS ----
    float* stg = exl + wslot * 272;               // reuse, wave-private
    *(float4*)(stg + (q << 6) + (l << 2)) = make_float4(v0, v1, v2, v3);

    // each lane computes 4 output columns j = 4l..4l+3 (same MAC order as
    // mm64_attn_body / mm64_plain_body -> bit-identical acc values)
    float4 A0 = make_float4(0, 0, 0, 0), A1 = make_float4(0, 0, 0, 0);
    float4 A2 = make_float4(0, 0, 0, 0), A3 = make_float4(0, 0, 0, 0);
#pragma unroll
    for (int kk = 0; kk < 16; kk++) {
        float4 hk = *(const float4*)(stg + (q << 6) + (kk << 2));
        const float* wr = WgL + (kk << 8) + (l << 2);
        float4 w0 = *(const float4*)(wr);
        float4 w1 = *(const float4*)(wr + 64);
        float4 w2 = *(const float4*)(wr + 128);
        float4 w3 = *(const float4*)(wr + 192);
        A0.x += hk.x * w0.x; A0.y += hk.x * w0.y; A0.z += hk.x * w0.z; A0.w += hk.x * w0.w;
        A1.x += hk.y * w1.x; A1.y += hk.y * w1.y; A1.z += hk.y * w1.z; A1.w += hk.y * w1.w;
        A2.x += hk.z * w2.x; A2.y += hk.z * w2.y; A2.z += hk.z * w2.z; A2.w += hk.z * w2.w;
        A3.x += hk.w * w3.x; A3.y += hk.w * w3.y; A3.z += hk.w * w3.z; A3.w += hk.w * w3.w;
    }
    float o0 = (A0.x + A1.x) + (A2.x + A3.x);
    float o1 = (A0.y + A1.y) + (A2.y + A3.y);
    float o2 = (A0.z + A1.z) + (A2.z + A3.z);
    float o3 = (A0.w + A1.w) + (A2.w + A3.w);

    if (MODE == 0) {
        if (nv) {
            ushort4 pk = make_ushort4(f2bf(o0), f2bf(o1), f2bf(o2), f2bf(o3));
            *(ushort4*)(hw16_out + (size_t)n * HIDN + (l << 2)) = pk;
        }
        float4 asw = *(const float4*)(att_s_w + (l << 2));
        float4 adw = *(const float4*)(att_d_w + (l << 2));
        float ts = (o0 * asw.x + o1 * asw.y) + (o2 * asw.z + o3 * asw.w);
        float td = (o0 * adw.x + o1 * adw.y) + (o2 * adw.z + o3 * adw.w);
        ts += __shfl_xor(ts, 1); ts += __shfl_xor(ts, 2);
        td += __shfl_xor(td, 1); td += __shfl_xor(td, 2);
        if (nv && (l & 3) == 0) {
            a_s_out[(size_t)n * NHEAD + (l >> 2)] = ts;
            a_d_out[(size_t)n * NHEAD + (l >> 2)] = td;
        }
    } else {
        if (nv) {
            float4 bo = *(const float4*)(bias_out + (l << 2));
            *(float4*)(out + (size_t)n * HIDN + (l << 2)) =
                make_float4(o0 + bo.x, o1 + bo.y, o2 + bo.z, o3 + bo.w);
        }
    }
}

extern "C" void kernel_launch(void* const* d_in, const int* in_sizes, int n_in,
                              void* d_out, int out_size, void* d_ws, size_t ws_size,
                              hipStream_t stream) {
    const float* x      = (const float*)d_in[0];
    const int*   ei     = (const int*)d_in[1];
    const float* eattr  = (const float*)d_in[2];
    const float* w_ne1  = (const float*)d_in[3];
    const float* b_ne1  = (const float*)d_in[4];
    const float* w_ne2  = (const float*)d_in[5];
    const float* b_ne2  = (const float*)d_in[6];
    const float* w_ee   = (const float*)d_in[7];
    const float* b_ee   = (const float*)d_in[8];
    const float* w_gat  = (const float*)d_in[9];
    const float* w_eg   = (const float*)d_in[10];
    const float* att_src= (const float*)d_in[11];
    const float* att_dst= (const float*)d_in[12];
    const float* att_edge=(const float*)d_in[13];
    const float* b_gat  = (const float*)d_in[14];
    const float* ln_g   = (const float*)d_in[15];
    const float* ln_b   = (const float*)d_in[16];
    const float* w_out  = (const float*)d_in[17];
    const float* b_out  = (const float*)d_in[18];

    const int N = in_sizes[0] / NIN;
    const int E = in_sizes[2];

    // -------- workspace layout --------
    float* ws   = (float*)d_ws;
    float* h    = ws;                                   // N*64
    float* hid  = h + (size_t)N * 64;                   // N*64 (dead after mid)
    unsigned short* hw16 = (unsigned short*)(hid + (size_t)N * 64);  // N*64 u16
    float* a_s  = (float*)(hw16 + (size_t)N * 64);      // N*4
    float* a_d  = a_s + (size_t)N * 4;                  // N*4
    float* c1   = a_d + (size_t)N * 4;                  // 12
    float* c0   = c1 + 12;                              // 12
    int2*  eca  = (int2*)(c0 + 12);                     // E int2
    unsigned* rank = (unsigned*)(eca + (size_t)E);      // E
    unsigned* deg  = rank + (size_t)E;                  // N<<DEGPAD (line-padded)
    unsigned* rp   = deg + ((size_t)N << DEGPAD);       // N+1
    unsigned* bsum = rp + (size_t)N + 1;                // <=1024

    // ping-pong B-set carved from hid (dead after mid_kernel)
    unsigned short* hw16b = (unsigned short*)hid;       // N*64 u16 (12.8 MB)
    float* a_sb = (float*)(hw16b + (size_t)N * 64);     // N*4
    float* a_db = a_sb + (size_t)N * 4;                 // N*4

    dim3 blk(256);
    int edgeBlocks = (E + 255) / 256;
    int encBlocks  = (int)(((size_t)N * 64 + 255) / 256);
    int quadBlocks = (int)(((size_t)((N + 3) / 4) * 64 + 255) / 256);
    int nodeBlocks = (N + 255) / 256;
    int mmBlocks = 2048;            // 8192 waves, grid-stride over nodes
    int mmWaves  = mmBlocks * 4;

    // K0: reset histogram counters
    hipMemsetAsync(deg, 0, ((size_t)N << DEGPAD) * sizeof(unsigned), stream);

    // K1: hist (atomic-rate-bound, low-VGPR) | encode1 | consts
    pre_kernel<<<edgeBlocks + encBlocks + 1, blk, 0, stream>>>(
        ei, deg, rank, E,
        x, w_ne1, b_ne1, hid, N,
        w_ee, b_ee, w_eg, att_edge, c1, c0,
        edgeBlocks, encBlocks);

    // K2: scan1 | encoder mm (hid@w2 -> h)
    mid_kernel<<<nodeBlocks + mmBlocks, blk, 0, stream>>>(
        deg, rp, bsum, N, hid, w_ne2, b_ne2, h, nodeBlocks, mmWaves);

    // K3: merged scan2+scan3
    scan23_kernel<<<nodeBlocks, blk, 0, stream>>>(rp, bsum, N, E);

    // K4: csr scatter | layer-0 attn transform (h -> hw16/a_s/a_d, A-set)
    sca_kernel<<<edgeBlocks + mmBlocks, blk, 0, stream>>>(
        ei, eattr, rp, rank, eca, E,
        h, w_gat, att_src, att_dst, hw16, a_s, a_d, N,
        edgeBlocks, mmWaves);

    // K5: gat layer 0 (reads A) + fused layer-1 transform (writes B)
    gat_fused_x_kernel<0><<<quadBlocks, blk, 0, stream>>>(
        rp, eca, hw16, a_s, a_d, c1 + 0, c0 + 0,
        h, b_gat + 0, ln_g + 0, ln_b + 0, N,
        w_gat + (size_t)1 * 4096, att_src + 64, att_dst + 64, nullptr,
        hw16b, a_sb, a_db, nullptr);

    // K6: gat layer 1 (reads B) + fused layer-2 transform (writes A)
    gat_fused_x_kernel<0><<<quadBlocks, blk, 0, stream>>>(
        rp, eca, hw16b, a_sb, a_db, c1 + 4, c0 + 4,
        h, b_gat + 64, ln_g + 64, ln_b + 64, N,
        w_gat + (size_t)2 * 4096, att_src + 2 * 64, att_dst + 2 * 64, nullptr,
        hw16, a_s, a_d, nullptr);

    // K7: gat layer 2 (reads A) + fused output projection -> d_out
    gat_fused_x_kernel<1><<<quadBlocks, blk, 0, stream>>>(
        rp, eca, hw16, a_s, a_d, c1 + 8, c0 + 8,
        h, b_gat + 2 * 64, ln_g + 2 * 64, ln_b + 2 * 64, N,
        w_out, nullptr, nullptr, b_out,
        nullptr, nullptr, nullptr, (float*)d_out);
}